// Round 2
// baseline (49150.671 us; speedup 1.0000x reference)
//
#include <hip/hip_runtime.h>
#include <cstddef>
#include <cstdint>

// Model dims (fixed by reference)
#define T_LEN 512
#define B_SZ  128
#define MD    31
#define E_SZ  256
#define H_SZ  512
#define S_SZ  128
#define K_TOT 768          // 512 (h) + 256 (phi)
#define GAMMA_F 1.0f
#define LOG001   -4.605170185988091f   // log(0.01)
#define HALF_L2PI 0.9189385332046727f  // 0.5*log(2*pi)

// LDS activation layout: 4 segments of 192 floats, each padded +4 (seg stride 196)
// so the 4 K-split lanes hit distinct bank groups; row stride 788 floats.
#define SEG_F   192
#define SEGP    196
#define APITCH  788

// ---------------- zero/init: h0 = 0, out = 0 (ws/out poisoned 0xAA each run) ----------------
__global__ void zero_init(float* __restrict__ h0, float* __restrict__ out) {
    int i = blockIdx.x * blockDim.x + threadIdx.x;
    if (i < B_SZ * H_SZ) h0[i] = 0.f;
    if (i == 0) out[0] = 0.f;
}

// ---------------- pack W: wpack[col][768] = [W_hh[col][0:512] | W_ih[col][0:256]] ------------
// col = gate*512 + j, gate order r,z,n (torch GRUCell layout)
__global__ void pack_w(const float* __restrict__ W_ih, const float* __restrict__ W_hh,
                       float* __restrict__ wpack) {
    const int n = 1536 * K_TOT;
    for (int i = blockIdx.x * blockDim.x + threadIdx.x; i < n; i += gridDim.x * blockDim.x) {
        int col = i / K_TOT, k = i - col * K_TOT;
        wpack[i] = (k < H_SZ) ? W_hh[col * H_SZ + k] : W_ih[col * E_SZ + (k - H_SZ)];
    }
}

// ---------------- embed: phi[row][e] = relu(b_embed[e] + sum_m x[row][m]*W_embed[e][m]) -----
__global__ __launch_bounds__(256) void embed_phi(
    const float* __restrict__ x, const float* __restrict__ W_embed,
    const float* __restrict__ b_embed, float* __restrict__ phi) {
    __shared__ float xs[8][32];
    const int e = threadIdx.x;  // 0..255, one output col per thread
    float w[MD];
    #pragma unroll
    for (int m = 0; m < MD; ++m) w[m] = W_embed[e * MD + m];
    const float be = b_embed[e];
    const int nblocks = (T_LEN * B_SZ) / 8;
    for (int rb = blockIdx.x; rb < nblocks; rb += gridDim.x) {
        const int r0 = rb * 8;
        if (threadIdx.x < 8 * MD)
            xs[threadIdx.x / MD][threadIdx.x % MD] = x[(size_t)r0 * MD + threadIdx.x];
        __syncthreads();
        #pragma unroll
        for (int i = 0; i < 8; ++i) {
            float acc = be;
            #pragma unroll
            for (int m = 0; m < MD; ++m) acc = fmaf(xs[i][m], w[m], acc);
            phi[(size_t)(r0 + i) * E_SZ + e] = fmaxf(acc, 0.f);
        }
        __syncthreads();
    }
}

// ---------------- one GRU step, latency-fixed ------------------------------------------------
// grid (32 j-tiles, 8 b-tiles), block 1024 = 16 waves/CU.
// tid: ks = tid&3 (K-split of 192), jl = (tid>>2)&15 (hidden unit), bl = tid>>6 (batch row;
// one batch row per wave -> LDS act reads are broadcasts).
// act LDS = [h(512) | phi(256)] unified, swizzled per-192-segment (+4 pad).
__global__ __launch_bounds__(1024, 4) void gru_step(
    const float* __restrict__ wpack, const float* __restrict__ phi_t,
    const float* __restrict__ h_cur, float* __restrict__ h_nxt,
    float* __restrict__ hs_t,
    const float* __restrict__ b_ih, const float* __restrict__ b_hh) {
    __shared__ float act_s[16 * APITCH];

    const int tid = threadIdx.x;
    const int b0 = blockIdx.y * 16;
    const int j0 = blockIdx.x * 16;

    // --- stage act: 16 rows x 768 floats = 3072 float4, 3 per thread ---
    #pragma unroll
    for (int i = 0; i < 3; ++i) {
        const int flat = tid + i * 1024;            // float4 index, [0,3072)
        const int row = flat / 192, q = flat - row * 192;
        float4 v;
        if (q < 128) v = *(const float4*)(h_cur + (size_t)(b0 + row) * H_SZ + q * 4);
        else         v = *(const float4*)(phi_t + (size_t)(b0 + row) * E_SZ + (q - 128) * 4);
        const int seg = q / 48, qq = q - seg * 48;
        *(float4*)(act_s + row * APITCH + seg * SEGP + qq * 4) = v;
    }
    __syncthreads();

    // --- compute: each thread = one (b,j) cell's 3 gates over its 192-K slice ---
    const int ks = tid & 3, jl = (tid >> 2) & 15, bl = tid >> 6;
    const int j = j0 + jl;
    const float* __restrict__ wr = wpack + (size_t)j * K_TOT + ks * SEG_F;
    const float* __restrict__ wz = wpack + (size_t)(512 + j) * K_TOT + ks * SEG_F;
    const float* __restrict__ wn = wpack + (size_t)(1024 + j) * K_TOT + ks * SEG_F;
    const float* __restrict__ as = act_s + bl * APITCH + ks * SEGP;

    float pr = 0.f, pz = 0.f, pnh = 0.f, pnx = 0.f;  // n keeps h-part / phi-part separate
    const int kbase = ks * SEG_F;
    #pragma unroll 4
    for (int i = 0; i < 48; ++i) {
        const float4 a4 = *(const float4*)(as + i * 4);
        const float4 r4 = *(const float4*)(wr + i * 4);
        const float4 z4 = *(const float4*)(wz + i * 4);
        const float4 n4 = *(const float4*)(wn + i * 4);
        pr = fmaf(r4.x, a4.x, pr); pr = fmaf(r4.y, a4.y, pr);
        pr = fmaf(r4.z, a4.z, pr); pr = fmaf(r4.w, a4.w, pr);
        pz = fmaf(z4.x, a4.x, pz); pz = fmaf(z4.y, a4.y, pz);
        pz = fmaf(z4.z, a4.z, pz); pz = fmaf(z4.w, a4.w, pz);
        if (kbase + i * 4 < H_SZ) {
            pnh = fmaf(n4.x, a4.x, pnh); pnh = fmaf(n4.y, a4.y, pnh);
            pnh = fmaf(n4.z, a4.z, pnh); pnh = fmaf(n4.w, a4.w, pnh);
        } else {
            pnx = fmaf(n4.x, a4.x, pnx); pnx = fmaf(n4.y, a4.y, pnx);
            pnx = fmaf(n4.z, a4.z, pnx); pnx = fmaf(n4.w, a4.w, pnx);
        }
    }
    // --- reduce the 4 K-split lanes (adjacent lanes in-wave) ---
    pr  += __shfl_xor(pr, 1);  pr  += __shfl_xor(pr, 2);
    pz  += __shfl_xor(pz, 1);  pz  += __shfl_xor(pz, 2);
    pnh += __shfl_xor(pnh, 1); pnh += __shfl_xor(pnh, 2);
    pnx += __shfl_xor(pnx, 1); pnx += __shfl_xor(pnx, 2);

    if (ks == 0) {
        const float r = 1.f / (1.f + expf(-(pr + b_ih[j] + b_hh[j])));
        const float z = 1.f / (1.f + expf(-(pz + b_ih[512 + j] + b_hh[512 + j])));
        const float xn = pnx + b_ih[1024 + j];
        const float hn = pnh + b_hh[1024 + j];
        const float n = tanhf(fmaf(r, hn, xn));
        const float hold = act_s[bl * APITCH + (j / SEG_F) * SEGP + (j % SEG_F)];
        const float hnew = fmaf(z, hold - n, n);   // (1-z)*n + z*h
        h_nxt[(size_t)(b0 + bl) * H_SZ + j] = hnew;
        hs_t[(size_t)(b0 + bl) * H_SZ + j] = hold; // scan collects pre-update state
    }
}

// ---------------- he + mu/logvar + loss, fused. 16 rows per block, rows t>=1 only -----------
__global__ __launch_bounds__(256) void he_loss(
    const float* __restrict__ hs, const float* __restrict__ W_he, const float* __restrict__ b_he,
    const float* __restrict__ W_mu, const float* __restrict__ b_mu,
    const float* __restrict__ W_lv, const float* __restrict__ b_lv,
    const float* __restrict__ h_inf, const float* __restrict__ time_inf,
    const float* __restrict__ base_int, const float* __restrict__ x,
    const float* __restrict__ t_in, const float* __restrict__ mask,
    float* __restrict__ out) {
    __shared__ float he_s[16][129];
    __shared__ float wmu_s[MD][129];
    __shared__ float wlv_s[MD][129];
    __shared__ float hinf_s[S_SZ];
    __shared__ float red[4];
    for (int i = threadIdx.x; i < MD * S_SZ; i += 256) {
        wmu_s[i / S_SZ][i % S_SZ] = W_mu[i];
        wlv_s[i / S_SZ][i % S_SZ] = W_lv[i];
    }
    if (threadIdx.x < S_SZ) hinf_s[threadIdx.x] = h_inf[threadIdx.x];
    __syncthreads();

    const int row0 = B_SZ + blockIdx.x * 16;   // skip t=0 (rows 0..127)
    {
        const int c = threadIdx.x & 127, rg = threadIdx.x >> 7;
        const float* __restrict__ wrow = W_he + (size_t)c * H_SZ;
        float acc[8];
        #pragma unroll
        for (int i = 0; i < 8; ++i) acc[i] = b_he[c];
        for (int k = 0; k < H_SZ; k += 4) {
            const float4 w4 = *(const float4*)(wrow + k);
            #pragma unroll
            for (int i = 0; i < 8; ++i) {
                const float4 h4 = *(const float4*)(hs + (size_t)(row0 + rg * 8 + i) * H_SZ + k);
                acc[i] = fmaf(w4.x, h4.x, acc[i]);
                acc[i] = fmaf(w4.y, h4.y, acc[i]);
                acc[i] = fmaf(w4.z, h4.z, acc[i]);
                acc[i] = fmaf(w4.w, h4.w, acc[i]);
            }
        }
        #pragma unroll
        for (int i = 0; i < 8; ++i) he_s[rg * 8 + i][c] = fmaxf(acc[i], 0.f);
    }
    __syncthreads();
    const int r = threadIdx.x >> 4, q = threadIdx.x & 15;
    const int row = row0 + r;
    const float mk = mask[row];
    float lacc = 0.f;
    #pragma unroll
    for (int pass = 0; pass < 2; ++pass) {
        const int m = q + pass * 16;
        if (m < MD) {
            float mu = b_mu[m], lv = b_lv[m];
            for (int c2 = 0; c2 < S_SZ; ++c2) {
                const float h = he_s[r][c2];
                mu = fmaf(h, wmu_s[m][c2], mu);
                lv = fmaf(h, wlv_s[m][c2], lv);
            }
            const float ls    = fmaxf(0.5f * lv, LOG001);  // log(max(exp(.5lv), 0.01))
            const float inv_s = expf(-ls);
            const float zz    = (x[(size_t)row * MD + m] - mu) * inv_s;
            lacc += (0.5f * zz * zz + ls + HALF_L2PI) * mk;
        }
    }
    if (q == 0) {
        float past = 0.f;
        for (int c2 = 0; c2 < S_SZ; ++c2) past = fmaf(he_s[r][c2], hinf_s[c2], past);
        const float ti = time_inf[0], bi = base_int[0];
        const float dt = t_in[(size_t)row * 2 + 1];
        const float term1 = past + ti * dt + bi;
        const float tll = term1 + (expf(past + bi) - expf(term1)) / ti;
        lacc += GAMMA_F * (-tll) * mk;
    }
    #pragma unroll
    for (int off = 32; off > 0; off >>= 1) lacc += __shfl_down(lacc, off, 64);
    if ((threadIdx.x & 63) == 0) red[threadIdx.x >> 6] = lacc;
    __syncthreads();
    if (threadIdx.x == 0) atomicAdd(out, red[0] + red[1] + red[2] + red[3]);
}

extern "C" void kernel_launch(void* const* d_in, const int* in_sizes, int n_in,
                              void* d_out, int out_size, void* d_ws, size_t ws_size,
                              hipStream_t stream) {
    const float* x       = (const float*)d_in[0];
    const float* t_in    = (const float*)d_in[1];
    const float* mask    = (const float*)d_in[2];
    const float* W_embed = (const float*)d_in[3];
    const float* b_embed = (const float*)d_in[4];
    const float* W_ih    = (const float*)d_in[5];
    const float* b_ih    = (const float*)d_in[6];
    const float* W_hh    = (const float*)d_in[7];
    const float* b_hh    = (const float*)d_in[8];
    const float* W_he    = (const float*)d_in[9];
    const float* b_he    = (const float*)d_in[10];
    const float* W_mu    = (const float*)d_in[11];
    const float* b_mu    = (const float*)d_in[12];
    const float* W_lv    = (const float*)d_in[13];
    const float* b_lv    = (const float*)d_in[14];
    const float* h_inf   = (const float*)d_in[15];
    const float* tinf    = (const float*)d_in[16];
    const float* bint    = (const float*)d_in[17];
    float* out = (float*)d_out;

    // ws layout (bytes): phi 67.1MB | hs 134.2MB | wpack 4.7MB | hA | hB  => 197MB total
    char* ws = (char*)d_ws;
    const size_t OFF_PHI = 0, OFF_HS = 67108864ull, OFF_WPACK = 201326592ull,
                 OFF_HA = 206045184ull, OFF_HB = 206307328ull, TOTAL = 206569472ull;
    if (ws_size < TOTAL) return;
    float* phi   = (float*)(ws + OFF_PHI);
    float* hs    = (float*)(ws + OFF_HS);
    float* wpack = (float*)(ws + OFF_WPACK);
    float* hA    = (float*)(ws + OFF_HA);
    float* hB    = (float*)(ws + OFF_HB);

    zero_init<<<dim3((B_SZ * H_SZ + 255) / 256), 256, 0, stream>>>(hA, out);
    pack_w<<<dim3(512), 256, 0, stream>>>(W_ih, W_hh, wpack);
    embed_phi<<<dim3(1024), 256, 0, stream>>>(x, W_embed, b_embed, phi);
    for (int t = 0; t < T_LEN; ++t) {
        const float* hc = (t & 1) ? hB : hA;
        float* hn       = (t & 1) ? hA : hB;
        gru_step<<<dim3(32, 8), 1024, 0, stream>>>(wpack, phi + (size_t)t * B_SZ * E_SZ,
                                                   hc, hn, hs + (size_t)t * B_SZ * H_SZ,
                                                   b_ih, b_hh);
    }
    he_loss<<<dim3((T_LEN - 1) * B_SZ / 16), 256, 0, stream>>>(
        hs, W_he, b_he, W_mu, b_mu, W_lv, b_lv, h_inf, tinf, bint, x, t_in, mask, out);
}

// Round 3
// 9298.479 us; speedup vs baseline: 5.2859x; 5.2859x over previous
//
#include <hip/hip_runtime.h>
#include <cstddef>
#include <cstdint>

// Model dims (fixed by reference)
#define T_LEN 512
#define B_SZ  128
#define MD    31
#define E_SZ  256
#define H_SZ  512
#define S_SZ  128
#define GAMMA_F 1.0f
#define LOG001   -4.605170185988091f   // log(0.01)
#define HALF_L2PI 0.9189385332046727f  // 0.5*log(2*pi)

typedef __attribute__((ext_vector_type(8))) short bf16x8;   // 8 bf16 in 4 VGPRs
typedef __attribute__((ext_vector_type(4))) float f32x4;

#define ACT_PITCH 776   // 768 + 8 bf16 pad (keeps 16B align, breaks pow2 bank stride)

__device__ inline unsigned short f2bf(float f) {   // fp32 -> bf16 bits, RNE
    union { float f; unsigned u; } v; v.f = f;
    unsigned r = v.u + 0x7FFFu + ((v.u >> 16) & 1u);
    return (unsigned short)(r >> 16);
}

// ---------------- zero/init: hA(fp32+bf16)=0, counters=0, out=0 ----------------
__global__ void zero_init(float* __restrict__ hf32A, unsigned* __restrict__ hb16A_u32,
                          unsigned* __restrict__ cnt, float* __restrict__ out) {
    int i = blockIdx.x * blockDim.x + threadIdx.x;
    if (i < B_SZ * H_SZ) hf32A[i] = 0.f;
    if (i < B_SZ * H_SZ / 2) hb16A_u32[i] = 0u;
    if (i < 8) cnt[i] = 0u;
    if (i == 0) out[0] = 0.f;
}

// ---------------- pack W -> bf16: wpack[col][768] = [W_hh[col][0:512] | W_ih[col][0:256]] ----
// col = gate*512 + j, gate order r,z,n (torch GRUCell layout). K-contig rows = MFMA B^T layout.
__global__ void pack_w(const float* __restrict__ W_ih, const float* __restrict__ W_hh,
                       unsigned short* __restrict__ wpack) {
    const int n = 1536 * 768;
    for (int i = blockIdx.x * blockDim.x + threadIdx.x; i < n; i += gridDim.x * blockDim.x) {
        int col = i / 768, k = i - col * 768;
        float v = (k < H_SZ) ? W_hh[col * H_SZ + k] : W_ih[col * E_SZ + (k - H_SZ)];
        wpack[i] = f2bf(v);
    }
}

// ---------------- embed: phi_bf16[row][e] = bf16(relu(b_embed[e] + x[row]·W_embed[e])) -------
__global__ __launch_bounds__(256) void embed_phi(
    const float* __restrict__ x, const float* __restrict__ W_embed,
    const float* __restrict__ b_embed, unsigned short* __restrict__ phi) {
    __shared__ float xs[8][32];
    const int e = threadIdx.x;
    float w[MD];
    #pragma unroll
    for (int m = 0; m < MD; ++m) w[m] = W_embed[e * MD + m];
    const float be = b_embed[e];
    const int nblocks = (T_LEN * B_SZ) / 8;
    for (int rb = blockIdx.x; rb < nblocks; rb += gridDim.x) {
        const int r0 = rb * 8;
        if (threadIdx.x < 8 * MD)
            xs[threadIdx.x / MD][threadIdx.x % MD] = x[(size_t)r0 * MD + threadIdx.x];
        __syncthreads();
        #pragma unroll
        for (int i = 0; i < 8; ++i) {
            float acc = be;
            #pragma unroll
            for (int m = 0; m < MD; ++m) acc = fmaf(xs[i][m], w[m], acc);
            phi[(size_t)(r0 + i) * E_SZ + e] = f2bf(fmaxf(acc, 0.f));
        }
        __syncthreads();
    }
}

// ---------------- persistent GRU recurrence --------------------------------------------------
// grid 256 = 32 j-groups (ct) x 8 b-groups (bt = blockIdx&7, XCD round-robin locality).
// block 384 thr = 6 waves = (gate gt in {r,z,n}) x (K-half kh: 0 => k[0,512) h-part,
// 1 => k[512,768) phi-part). Output tile per block: 16 b-rows x (3 x 16 cols).
// State: h fp32 (exact), bf16 shadow for MFMA A. Cross-block h exchange via global +
// per-bt-group monotonic barrier (agent-scope release/acquire).
__global__ __launch_bounds__(384) void gru_persist(
    const unsigned short* __restrict__ wpack, const unsigned short* __restrict__ phi,
    float* __restrict__ hf32A, float* __restrict__ hf32B,
    unsigned short* __restrict__ hb16A, unsigned short* __restrict__ hb16B,
    float* __restrict__ hs,
    const float* __restrict__ b_ih, const float* __restrict__ b_hh,
    unsigned* __restrict__ cnt) {
    __shared__ short act_s[16 * ACT_PITCH];      // 24.8 KB bf16 act tile [16 rows][768+pad]
    __shared__ float red_s[6][256];              // 6 KB partial C tiles (row*16+col)

    const int tid = threadIdx.x;
    const int bt = blockIdx.x & 7, ct = blockIdx.x >> 3;
    const int b0 = bt * 16, j0 = ct * 16;

    const int wid = tid >> 6, L = tid & 63;
    const int gt = wid >> 1, kh = wid & 1;
    const int n_loc = L & 15, kb = L >> 4;       // B col / A row = L&15; k-block = L>>4
    const unsigned short* __restrict__ wrow =
        wpack + (size_t)(gt * 512 + j0 + n_loc) * 768;

    // gate-phase invariants (threads 0..255: cell b = b0 + (tid>>4), j = j0 + (tid&15))
    const int gb = tid >> 4, gj = tid & 15;
    float bias_r = 0.f, bias_z = 0.f, bias_xn = 0.f, bias_hn = 0.f;
    if (tid < 256) {
        const int j = j0 + gj;
        bias_r  = b_ih[j] + b_hh[j];
        bias_z  = b_ih[512 + j] + b_hh[512 + j];
        bias_xn = b_ih[1024 + j];
        bias_hn = b_hh[1024 + j];
    }

    for (int t = 0; t < T_LEN; ++t) {
        const unsigned short* __restrict__ hb_cur = (t & 1) ? hb16B : hb16A;
        unsigned short* __restrict__ hb_nxt       = (t & 1) ? hb16A : hb16B;
        const float* __restrict__ hf_cur          = (t & 1) ? hf32B : hf32A;
        float* __restrict__ hf_nxt                = (t & 1) ? hf32A : hf32B;
        const unsigned short* __restrict__ phi_t  = phi + (size_t)t * B_SZ * E_SZ;

        // --- stage act tile: 16 rows x 768 bf16 = 1536 chunks of 8, 4 per thread ---
        #pragma unroll
        for (int it = 0; it < 4; ++it) {
            const int c = tid + it * 384;
            const int m = c / 96, kc = (c - m * 96) * 8;
            bf16x8 v;
            if (kc < 512) v = *(const bf16x8*)(hb_cur + (size_t)(b0 + m) * H_SZ + kc);
            else          v = *(const bf16x8*)(phi_t + (size_t)(b0 + m) * E_SZ + (kc - 512));
            *(bf16x8*)(act_s + m * ACT_PITCH + kc) = v;
        }
        __syncthreads();

        // --- MFMA: each wave = one 16x16 gate-tile over its K-half ---
        {
            f32x4 acc = {0.f, 0.f, 0.f, 0.f};
            const int k_beg = kh ? 512 : 0, k_end = kh ? 768 : 512;
            #pragma unroll
            for (int k0 = k_beg; k0 < k_end; k0 += 32) {
                bf16x8 a = *(const bf16x8*)(act_s + n_loc * ACT_PITCH + k0 + kb * 8);
                bf16x8 b = *(const bf16x8*)(wrow + k0 + kb * 8);
                acc = __builtin_amdgcn_mfma_f32_16x16x32_bf16(a, b, acc, 0, 0, 0);
            }
            #pragma unroll
            for (int i = 0; i < 4; ++i)          // D: row=(L>>4)*4+i, col=L&15
                red_s[wid][(kb * 4 + i) * 16 + n_loc] = acc[i];
        }
        __syncthreads();

        // --- gate math + state update (threads 0..255, one cell each) ---
        if (tid < 256) {
            const int cell = gb * 16 + gj;
            const int b = b0 + gb, j = j0 + gj;
            const float pre_r = red_s[0][cell] + red_s[1][cell] + bias_r;
            const float pre_z = red_s[2][cell] + red_s[3][cell] + bias_z;
            const float hn    = red_s[4][cell] + bias_hn;   // h-part of n gate
            const float xn    = red_s[5][cell] + bias_xn;   // phi-part of n gate
            const float r = 1.f / (1.f + expf(-pre_r));
            const float z = 1.f / (1.f + expf(-pre_z));
            const float n = tanhf(fmaf(r, hn, xn));
            const float hold = hf_cur[(size_t)b * H_SZ + j];
            const float hnew = fmaf(z, hold - n, n);        // (1-z)*n + z*h
            hf_nxt[(size_t)b * H_SZ + j] = hnew;
            hb_nxt[(size_t)b * H_SZ + j] = f2bf(hnew);
            if (t < T_LEN - 1)                               // hs[t+1] = state after step t
                hs[(size_t)(t + 1) * B_SZ * H_SZ + (size_t)b * H_SZ + j] = hnew;
        }
        __syncthreads();

        // --- bt-group barrier (32 blocks share this b-slice's h) ---
        if (tid == 0) {
            __threadfence();                                  // agent-scope release of h stores
            atomicAdd(&cnt[bt], 1u);
            const unsigned target = 32u * (unsigned)(t + 1);
            while (__hip_atomic_load(&cnt[bt], __ATOMIC_ACQUIRE,
                                     __HIP_MEMORY_SCOPE_AGENT) < target)
                __builtin_amdgcn_s_sleep(2);
        }
        __syncthreads();
    }
}

// ---------------- he + mu/logvar + loss, fused (unchanged, proven) --------------------------
__global__ __launch_bounds__(256) void he_loss(
    const float* __restrict__ hs, const float* __restrict__ W_he, const float* __restrict__ b_he,
    const float* __restrict__ W_mu, const float* __restrict__ b_mu,
    const float* __restrict__ W_lv, const float* __restrict__ b_lv,
    const float* __restrict__ h_inf, const float* __restrict__ time_inf,
    const float* __restrict__ base_int, const float* __restrict__ x,
    const float* __restrict__ t_in, const float* __restrict__ mask,
    float* __restrict__ out) {
    __shared__ float he_s[16][129];
    __shared__ float wmu_s[MD][129];
    __shared__ float wlv_s[MD][129];
    __shared__ float hinf_s[S_SZ];
    __shared__ float red[4];
    for (int i = threadIdx.x; i < MD * S_SZ; i += 256) {
        wmu_s[i / S_SZ][i % S_SZ] = W_mu[i];
        wlv_s[i / S_SZ][i % S_SZ] = W_lv[i];
    }
    if (threadIdx.x < S_SZ) hinf_s[threadIdx.x] = h_inf[threadIdx.x];
    __syncthreads();

    const int row0 = B_SZ + blockIdx.x * 16;   // skip t=0 rows
    {
        const int c = threadIdx.x & 127, rg = threadIdx.x >> 7;
        const float* __restrict__ wrow = W_he + (size_t)c * H_SZ;
        float acc[8];
        #pragma unroll
        for (int i = 0; i < 8; ++i) acc[i] = b_he[c];
        for (int k = 0; k < H_SZ; k += 4) {
            const float4 w4 = *(const float4*)(wrow + k);
            #pragma unroll
            for (int i = 0; i < 8; ++i) {
                const float4 h4 = *(const float4*)(hs + (size_t)(row0 + rg * 8 + i) * H_SZ + k);
                acc[i] = fmaf(w4.x, h4.x, acc[i]);
                acc[i] = fmaf(w4.y, h4.y, acc[i]);
                acc[i] = fmaf(w4.z, h4.z, acc[i]);
                acc[i] = fmaf(w4.w, h4.w, acc[i]);
            }
        }
        #pragma unroll
        for (int i = 0; i < 8; ++i) he_s[rg * 8 + i][c] = fmaxf(acc[i], 0.f);
    }
    __syncthreads();
    const int r = threadIdx.x >> 4, q = threadIdx.x & 15;
    const int row = row0 + r;
    const float mk = mask[row];
    float lacc = 0.f;
    #pragma unroll
    for (int pass = 0; pass < 2; ++pass) {
        const int m = q + pass * 16;
        if (m < MD) {
            float mu = b_mu[m], lv = b_lv[m];
            for (int c2 = 0; c2 < S_SZ; ++c2) {
                const float h = he_s[r][c2];
                mu = fmaf(h, wmu_s[m][c2], mu);
                lv = fmaf(h, wlv_s[m][c2], lv);
            }
            const float ls    = fmaxf(0.5f * lv, LOG001);
            const float inv_s = expf(-ls);
            const float zz    = (x[(size_t)row * MD + m] - mu) * inv_s;
            lacc += (0.5f * zz * zz + ls + HALF_L2PI) * mk;
        }
    }
    if (q == 0) {
        float past = 0.f;
        for (int c2 = 0; c2 < S_SZ; ++c2) past = fmaf(he_s[r][c2], hinf_s[c2], past);
        const float ti = time_inf[0], bi = base_int[0];
        const float dt = t_in[(size_t)row * 2 + 1];
        const float term1 = past + ti * dt + bi;
        const float tll = term1 + (expf(past + bi) - expf(term1)) / ti;
        lacc += GAMMA_F * (-tll) * mk;
    }
    #pragma unroll
    for (int off = 32; off > 0; off >>= 1) lacc += __shfl_down(lacc, off, 64);
    if ((threadIdx.x & 63) == 0) red[threadIdx.x >> 6] = lacc;
    __syncthreads();
    if (threadIdx.x == 0) atomicAdd(out, red[0] + red[1] + red[2] + red[3]);
}

extern "C" void kernel_launch(void* const* d_in, const int* in_sizes, int n_in,
                              void* d_out, int out_size, void* d_ws, size_t ws_size,
                              hipStream_t stream) {
    const float* x       = (const float*)d_in[0];
    const float* t_in    = (const float*)d_in[1];
    const float* mask    = (const float*)d_in[2];
    const float* W_embed = (const float*)d_in[3];
    const float* b_embed = (const float*)d_in[4];
    const float* W_ih    = (const float*)d_in[5];
    const float* b_ih    = (const float*)d_in[6];
    const float* W_hh    = (const float*)d_in[7];
    const float* b_hh    = (const float*)d_in[8];
    const float* W_he    = (const float*)d_in[9];
    const float* b_he    = (const float*)d_in[10];
    const float* W_mu    = (const float*)d_in[11];
    const float* b_mu    = (const float*)d_in[12];
    const float* W_lv    = (const float*)d_in[13];
    const float* b_lv    = (const float*)d_in[14];
    const float* h_inf   = (const float*)d_in[15];
    const float* tinf    = (const float*)d_in[16];
    const float* bint    = (const float*)d_in[17];
    float* out = (float*)d_out;

    // ws layout (bytes), 256-aligned:
    // phi_bf16 33.5M | hs fp32 134.2M | wpack_bf16 2.36M | hf32 A/B | hb16 A/B | counters
    char* ws = (char*)d_ws;
    const size_t OFF_PHI   = 0;
    const size_t OFF_HS    = 33554432ull;
    const size_t OFF_WP    = 167772160ull;
    const size_t OFF_HF32A = 170131456ull;
    const size_t OFF_HF32B = 170393600ull;
    const size_t OFF_HB16A = 170655744ull;
    const size_t OFF_HB16B = 170786816ull;
    const size_t OFF_CNT   = 170917888ull;
    const size_t TOTAL     = 170918144ull;
    if (ws_size < TOTAL) return;
    unsigned short* phi   = (unsigned short*)(ws + OFF_PHI);
    float*          hsbuf = (float*)(ws + OFF_HS);
    unsigned short* wpack = (unsigned short*)(ws + OFF_WP);
    float*          hf32A = (float*)(ws + OFF_HF32A);
    float*          hf32B = (float*)(ws + OFF_HF32B);
    unsigned short* hb16A = (unsigned short*)(ws + OFF_HB16A);
    unsigned short* hb16B = (unsigned short*)(ws + OFF_HB16B);
    unsigned*       cnt   = (unsigned*)(ws + OFF_CNT);

    zero_init<<<dim3((B_SZ * H_SZ + 255) / 256), 256, 0, stream>>>(
        hf32A, (unsigned*)hb16A, cnt, out);
    pack_w<<<dim3(512), 256, 0, stream>>>(W_ih, W_hh, wpack);
    embed_phi<<<dim3(1024), 256, 0, stream>>>(x, W_embed, b_embed, phi);

    void* args[] = {(void*)&wpack, (void*)&phi, (void*)&hf32A, (void*)&hf32B,
                    (void*)&hb16A, (void*)&hb16B, (void*)&hsbuf,
                    (void*)&b_ih, (void*)&b_hh, (void*)&cnt};
    hipLaunchCooperativeKernel((void*)gru_persist, dim3(256), dim3(384), args, 0, stream);

    he_loss<<<dim3((T_LEN - 1) * B_SZ / 16), 256, 0, stream>>>(
        hsbuf, W_he, b_he, W_mu, b_mu, W_lv, b_lv, h_inf, tinf, bint, x, t_in, mask, out);
}

// Round 4
// 2970.380 us; speedup vs baseline: 16.5469x; 3.1304x over previous
//
#include <hip/hip_runtime.h>
#include <cstddef>
#include <cstdint>

// Model dims (fixed by reference)
#define T_LEN 512
#define B_SZ  128
#define MD    31
#define E_SZ  256
#define H_SZ  512
#define S_SZ  128
#define GAMMA_F 1.0f
#define LOG001   -4.605170185988091f   // log(0.01)
#define HALF_L2PI 0.9189385332046727f  // 0.5*log(2*pi)

typedef __attribute__((ext_vector_type(8))) short bf16x8;   // 8 bf16 in 4 VGPRs
typedef __attribute__((ext_vector_type(4))) float f32x4;

#define ACT_PITCH 776   // 768 + 8 bf16 pad (16B-aligned rows, breaks pow2 bank stride)

__device__ inline unsigned short f2bf(float f) {   // fp32 -> bf16 bits, RNE
    union { float f; unsigned u; } v; v.f = f;
    unsigned r = v.u + 0x7FFFu + ((v.u >> 16) & 1u);
    return (unsigned short)(r >> 16);
}

// ---------------- zero/init: hA(fp32+bf16)=0, flags=0, out=0 ----------------
__global__ void zero_init(float* __restrict__ hf32A, unsigned* __restrict__ hb16A_u32,
                          unsigned* __restrict__ flags, float* __restrict__ out) {
    int i = blockIdx.x * blockDim.x + threadIdx.x;
    if (i < B_SZ * H_SZ) hf32A[i] = 0.f;
    if (i < B_SZ * H_SZ / 2) hb16A_u32[i] = 0u;
    if (i < 4096) flags[i] = 0u;   // 8 groups x 32 blocks x 64B stride
    if (i == 0) out[0] = 0.f;
}

// ---------------- pack W -> bf16: wpack[col][768] = [W_hh[col][0:512] | W_ih[col][0:256]] ----
// col = gate*512 + j, gate order r,z,n (torch GRUCell layout). K-contig rows = MFMA B^T layout.
__global__ void pack_w(const float* __restrict__ W_ih, const float* __restrict__ W_hh,
                       unsigned short* __restrict__ wpack) {
    const int n = 1536 * 768;
    for (int i = blockIdx.x * blockDim.x + threadIdx.x; i < n; i += gridDim.x * blockDim.x) {
        int col = i / 768, k = i - col * 768;
        float v = (k < H_SZ) ? W_hh[col * H_SZ + k] : W_ih[col * E_SZ + (k - H_SZ)];
        wpack[i] = f2bf(v);
    }
}

// ---------------- embed: phi_bf16[row][e] = bf16(relu(b_embed[e] + x[row]·W_embed[e])) -------
__global__ __launch_bounds__(256) void embed_phi(
    const float* __restrict__ x, const float* __restrict__ W_embed,
    const float* __restrict__ b_embed, unsigned short* __restrict__ phi) {
    __shared__ float xs[8][32];
    const int e = threadIdx.x;
    float w[MD];
    #pragma unroll
    for (int m = 0; m < MD; ++m) w[m] = W_embed[e * MD + m];
    const float be = b_embed[e];
    const int nblocks = (T_LEN * B_SZ) / 8;
    for (int rb = blockIdx.x; rb < nblocks; rb += gridDim.x) {
        const int r0 = rb * 8;
        if (threadIdx.x < 8 * MD)
            xs[threadIdx.x / MD][threadIdx.x % MD] = x[(size_t)r0 * MD + threadIdx.x];
        __syncthreads();
        #pragma unroll
        for (int i = 0; i < 8; ++i) {
            float acc = be;
            #pragma unroll
            for (int m = 0; m < MD; ++m) acc = fmaf(xs[i][m], w[m], acc);
            phi[(size_t)(r0 + i) * E_SZ + e] = f2bf(fmaxf(acc, 0.f));
        }
        __syncthreads();
    }
}

// ---------------- persistent GRU recurrence, fence-free --------------------------------------
// grid 256 = 32 j-groups (ct) x 8 b-groups (bt). block 384 = 6 waves = (gate r,z,n) x (K-half).
// Weights: B-fragments preloaded to VGPRs (loop-invariant). h exchange: relaxed AGENT atomics
// (sc1 -> LLC, the cross-XCD coherence point) => no wbl2 / no buffer_inv anywhere.
// Barrier: per-block monotonic flag (64B apart, no RMW) + wave-parallel relaxed polling.
__global__ __launch_bounds__(384) void gru_persist(
    const unsigned short* __restrict__ wpack, const unsigned short* __restrict__ phi,
    float* __restrict__ hf32A, float* __restrict__ hf32B,
    unsigned short* __restrict__ hb16A, unsigned short* __restrict__ hb16B,
    float* __restrict__ hs,
    const float* __restrict__ b_ih, const float* __restrict__ b_hh,
    unsigned* __restrict__ flags) {
    __shared__ __align__(16) short act_s[16 * ACT_PITCH];  // 24.8 KB bf16 act [16][768+pad]
    __shared__ float red_s[6][256];                        // 6 KB partial C tiles

    const int tid = threadIdx.x;
    const int bt = blockIdx.x & 7, ct = blockIdx.x >> 3;
    const int b0 = bt * 16, j0 = ct * 16;

    const int wid = tid >> 6, L = tid & 63;
    const int gt = wid >> 1, kh = wid & 1;
    const int n_loc = L & 15, kb = L >> 4;

    // --- preload loop-invariant B fragments into registers (16 x bf16x8 = 64 VGPRs) ---
    const unsigned short* __restrict__ wrow = wpack + (size_t)(gt * 512 + j0 + n_loc) * 768;
    const int k_beg = kh ? 512 : 0;
    bf16x8 Bf[16];
    #pragma unroll
    for (int i = 0; i < 16; ++i) {
        const int ii = kh ? (i & 7) : i;   // kh=1 has only 8 frags; duplicate harmlessly
        Bf[i] = *(const bf16x8*)(wrow + k_beg + ii * 32 + kb * 8);
    }

    // gate-phase invariants (threads 0..255: cell b = b0 + (tid>>4), j = j0 + (tid&15))
    const int gb = tid >> 4, gj = tid & 15;
    float bias_r = 0.f, bias_z = 0.f, bias_xn = 0.f, bias_hn = 0.f;
    if (tid < 256) {
        const int j = j0 + gj;
        bias_r  = b_ih[j] + b_hh[j];
        bias_z  = b_ih[512 + j] + b_hh[512 + j];
        bias_xn = b_ih[1024 + j];
        bias_hn = b_hh[1024 + j];
    }

    unsigned* __restrict__ flag_own = flags + (size_t)(bt * 32 + ct) * 16;
    unsigned* __restrict__ flag_poll = flags + (size_t)(bt * 32 + (L & 31)) * 16;

    for (int t = 0; t < T_LEN; ++t) {
        const unsigned short* hb_cur = (t & 1) ? hb16B : hb16A;
        unsigned short* hb_nxt       = (t & 1) ? hb16A : hb16B;
        const float* hf_cur          = (t & 1) ? hf32B : hf32A;
        float* hf_nxt                = (t & 1) ? hf32A : hf32B;
        const unsigned short* phi_t  = phi + (size_t)t * B_SZ * E_SZ;

        // --- stage act tile: 16 rows x 768 bf16 = 3072 u64 chunks, 8 per thread ---
        // h part via relaxed agent atomics (sc1 -> LLC-coherent), phi part plain (read-only)
        #pragma unroll
        for (int it = 0; it < 8; ++it) {
            const int c = tid + it * 384;            // u64 chunk id [0,3072)
            const int m = c / 192, q = c - m * 192;  // row, u64-within-row
            const int kc = q * 4;                    // bf16 index within 768
            unsigned long long v;
            if (kc < 512)
                v = __hip_atomic_load(
                        (const unsigned long long*)(hb_cur + (size_t)(b0 + m) * H_SZ + kc),
                        __ATOMIC_RELAXED, __HIP_MEMORY_SCOPE_AGENT);
            else
                v = *(const unsigned long long*)(phi_t + (size_t)(b0 + m) * E_SZ + (kc - 512));
            *(unsigned long long*)(act_s + m * ACT_PITCH + kc) = v;
        }
        __syncthreads();

        // --- MFMA from LDS(A) x VGPR(B) ---
        {
            f32x4 acc = {0.f, 0.f, 0.f, 0.f};
            const short* arow = act_s + n_loc * ACT_PITCH + kb * 8;
            if (kh == 0) {
                #pragma unroll
                for (int i = 0; i < 16; ++i) {
                    bf16x8 a = *(const bf16x8*)(arow + i * 32);
                    acc = __builtin_amdgcn_mfma_f32_16x16x32_bf16(a, Bf[i], acc, 0, 0, 0);
                }
            } else {
                #pragma unroll
                for (int i = 0; i < 8; ++i) {
                    bf16x8 a = *(const bf16x8*)(arow + 512 + i * 32);
                    acc = __builtin_amdgcn_mfma_f32_16x16x32_bf16(a, Bf[i], acc, 0, 0, 0);
                }
            }
            #pragma unroll
            for (int i = 0; i < 4; ++i)              // D: row=(L>>4)*4+i, col=L&15
                red_s[wid][(kb * 4 + i) * 16 + n_loc] = acc[i];
        }
        __syncthreads();

        // --- gate math + state update (threads 0..255, one cell each) ---
        if (tid < 256) {
            const int cell = gb * 16 + gj;
            const int b = b0 + gb, j = j0 + gj;
            const float pre_r = red_s[0][cell] + red_s[1][cell] + bias_r;
            const float pre_z = red_s[2][cell] + red_s[3][cell] + bias_z;
            const float hn    = red_s[4][cell] + bias_hn;   // h-part of n gate
            const float xn    = red_s[5][cell] + bias_xn;   // phi-part of n gate
            const float r = 1.f / (1.f + expf(-pre_r));
            const float z = 1.f / (1.f + expf(-pre_z));
            const float n = tanhf(fmaf(r, hn, xn));
            const float hold = __hip_atomic_load((float*)(hf_cur + (size_t)b * H_SZ + j),
                                                 __ATOMIC_RELAXED, __HIP_MEMORY_SCOPE_AGENT);
            const float hnew = fmaf(z, hold - n, n);        // (1-z)*n + z*h
            __hip_atomic_store(hf_nxt + (size_t)b * H_SZ + j, hnew,
                               __ATOMIC_RELAXED, __HIP_MEMORY_SCOPE_AGENT);
            __hip_atomic_store(hb_nxt + (size_t)b * H_SZ + j, f2bf(hnew),
                               __ATOMIC_RELAXED, __HIP_MEMORY_SCOPE_AGENT);
            if (t < T_LEN - 1)                               // hs[t+1] = state after step t
                hs[(size_t)(t + 1) * B_SZ * H_SZ + (size_t)b * H_SZ + j] = hnew;
        }
        __syncthreads();   // drains every wave's sc1 stores (vmcnt(0) before s_barrier)

        // --- fence-free bt-group barrier: monotonic flag + wave-parallel poll ---
        if (tid == 0)
            __hip_atomic_store(flag_own, (unsigned)(t + 1),
                               __ATOMIC_RELAXED, __HIP_MEMORY_SCOPE_AGENT);
        if (wid == 0) {
            const unsigned tgt = (unsigned)(t + 1);
            while (true) {
                unsigned v = __hip_atomic_load(flag_poll, __ATOMIC_RELAXED,
                                               __HIP_MEMORY_SCOPE_AGENT);
                if (__ballot(v >= tgt) == ~0ull) break;
                __builtin_amdgcn_s_sleep(1);
            }
        }
        __syncthreads();
    }
}

// ---------------- he + mu/logvar + loss, fused (unchanged, proven) --------------------------
__global__ __launch_bounds__(256) void he_loss(
    const float* __restrict__ hs, const float* __restrict__ W_he, const float* __restrict__ b_he,
    const float* __restrict__ W_mu, const float* __restrict__ b_mu,
    const float* __restrict__ W_lv, const float* __restrict__ b_lv,
    const float* __restrict__ h_inf, const float* __restrict__ time_inf,
    const float* __restrict__ base_int, const float* __restrict__ x,
    const float* __restrict__ t_in, const float* __restrict__ mask,
    float* __restrict__ out) {
    __shared__ float he_s[16][129];
    __shared__ float wmu_s[MD][129];
    __shared__ float wlv_s[MD][129];
    __shared__ float hinf_s[S_SZ];
    __shared__ float red[4];
    for (int i = threadIdx.x; i < MD * S_SZ; i += 256) {
        wmu_s[i / S_SZ][i % S_SZ] = W_mu[i];
        wlv_s[i / S_SZ][i % S_SZ] = W_lv[i];
    }
    if (threadIdx.x < S_SZ) hinf_s[threadIdx.x] = h_inf[threadIdx.x];
    __syncthreads();

    const int row0 = B_SZ + blockIdx.x * 16;   // skip t=0 rows
    {
        const int c = threadIdx.x & 127, rg = threadIdx.x >> 7;
        const float* __restrict__ wrow = W_he + (size_t)c * H_SZ;
        float acc[8];
        #pragma unroll
        for (int i = 0; i < 8; ++i) acc[i] = b_he[c];
        for (int k = 0; k < H_SZ; k += 4) {
            const float4 w4 = *(const float4*)(wrow + k);
            #pragma unroll
            for (int i = 0; i < 8; ++i) {
                const float4 h4 = *(const float4*)(hs + (size_t)(row0 + rg * 8 + i) * H_SZ + k);
                acc[i] = fmaf(w4.x, h4.x, acc[i]);
                acc[i] = fmaf(w4.y, h4.y, acc[i]);
                acc[i] = fmaf(w4.z, h4.z, acc[i]);
                acc[i] = fmaf(w4.w, h4.w, acc[i]);
            }
        }
        #pragma unroll
        for (int i = 0; i < 8; ++i) he_s[rg * 8 + i][c] = fmaxf(acc[i], 0.f);
    }
    __syncthreads();
    const int r = threadIdx.x >> 4, q = threadIdx.x & 15;
    const int row = row0 + r;
    const float mk = mask[row];
    float lacc = 0.f;
    #pragma unroll
    for (int pass = 0; pass < 2; ++pass) {
        const int m = q + pass * 16;
        if (m < MD) {
            float mu = b_mu[m], lv = b_lv[m];
            for (int c2 = 0; c2 < S_SZ; ++c2) {
                const float h = he_s[r][c2];
                mu = fmaf(h, wmu_s[m][c2], mu);
                lv = fmaf(h, wlv_s[m][c2], lv);
            }
            const float ls    = fmaxf(0.5f * lv, LOG001);
            const float inv_s = expf(-ls);
            const float zz    = (x[(size_t)row * MD + m] - mu) * inv_s;
            lacc += (0.5f * zz * zz + ls + HALF_L2PI) * mk;
        }
    }
    if (q == 0) {
        float past = 0.f;
        for (int c2 = 0; c2 < S_SZ; ++c2) past = fmaf(he_s[r][c2], hinf_s[c2], past);
        const float ti = time_inf[0], bi = base_int[0];
        const float dt = t_in[(size_t)row * 2 + 1];
        const float term1 = past + ti * dt + bi;
        const float tll = term1 + (expf(past + bi) - expf(term1)) / ti;
        lacc += GAMMA_F * (-tll) * mk;
    }
    #pragma unroll
    for (int off = 32; off > 0; off >>= 1) lacc += __shfl_down(lacc, off, 64);
    if ((threadIdx.x & 63) == 0) red[threadIdx.x >> 6] = lacc;
    __syncthreads();
    if (threadIdx.x == 0) atomicAdd(out, red[0] + red[1] + red[2] + red[3]);
}

extern "C" void kernel_launch(void* const* d_in, const int* in_sizes, int n_in,
                              void* d_out, int out_size, void* d_ws, size_t ws_size,
                              hipStream_t stream) {
    const float* x       = (const float*)d_in[0];
    const float* t_in    = (const float*)d_in[1];
    const float* mask    = (const float*)d_in[2];
    const float* W_embed = (const float*)d_in[3];
    const float* b_embed = (const float*)d_in[4];
    const float* W_ih    = (const float*)d_in[5];
    const float* b_ih    = (const float*)d_in[6];
    const float* W_hh    = (const float*)d_in[7];
    const float* b_hh    = (const float*)d_in[8];
    const float* W_he    = (const float*)d_in[9];
    const float* b_he    = (const float*)d_in[10];
    const float* W_mu    = (const float*)d_in[11];
    const float* b_mu    = (const float*)d_in[12];
    const float* W_lv    = (const float*)d_in[13];
    const float* b_lv    = (const float*)d_in[14];
    const float* h_inf   = (const float*)d_in[15];
    const float* tinf    = (const float*)d_in[16];
    const float* bint    = (const float*)d_in[17];
    float* out = (float*)d_out;

    // ws layout (bytes), 256-aligned:
    // phi_bf16 33.5M | hs fp32 134.2M | wpack_bf16 2.36M | hf32 A/B | hb16 A/B | flags 16K
    char* ws = (char*)d_ws;
    const size_t OFF_PHI   = 0;
    const size_t OFF_HS    = 33554432ull;
    const size_t OFF_WP    = 167772160ull;
    const size_t OFF_HF32A = 170131456ull;
    const size_t OFF_HF32B = 170393600ull;
    const size_t OFF_HB16A = 170655744ull;
    const size_t OFF_HB16B = 170786816ull;
    const size_t OFF_FLAGS = 170917888ull;
    const size_t TOTAL     = 170934272ull;
    if (ws_size < TOTAL) return;
    unsigned short* phi   = (unsigned short*)(ws + OFF_PHI);
    float*          hsbuf = (float*)(ws + OFF_HS);
    unsigned short* wpack = (unsigned short*)(ws + OFF_WP);
    float*          hf32A = (float*)(ws + OFF_HF32A);
    float*          hf32B = (float*)(ws + OFF_HF32B);
    unsigned short* hb16A = (unsigned short*)(ws + OFF_HB16A);
    unsigned short* hb16B = (unsigned short*)(ws + OFF_HB16B);
    unsigned*       flags = (unsigned*)(ws + OFF_FLAGS);

    zero_init<<<dim3(256), 256, 0, stream>>>(hf32A, (unsigned*)hb16A, flags, out);
    pack_w<<<dim3(512), 256, 0, stream>>>(W_ih, W_hh, wpack);
    embed_phi<<<dim3(1024), 256, 0, stream>>>(x, W_embed, b_embed, phi);

    void* args[] = {(void*)&wpack, (void*)&phi, (void*)&hf32A, (void*)&hf32B,
                    (void*)&hb16A, (void*)&hb16B, (void*)&hsbuf,
                    (void*)&b_ih, (void*)&b_hh, (void*)&flags};
    hipLaunchCooperativeKernel((void*)gru_persist, dim3(256), dim3(384), args, 0, stream);

    he_loss<<<dim3((T_LEN - 1) * B_SZ / 16), 256, 0, stream>>>(
        hsbuf, W_he, b_he, W_mu, b_mu, W_lv, b_lv, h_inf, tinf, bint, x, t_in, mask, out);
}

// Round 5
// 2674.394 us; speedup vs baseline: 18.3782x; 1.1107x over previous
//
#include <hip/hip_runtime.h>
#include <cstddef>
#include <cstdint>

// Model dims (fixed by reference)
#define T_LEN 512
#define B_SZ  128
#define MD    31
#define E_SZ  256
#define H_SZ  512
#define S_SZ  128
#define GAMMA_F 1.0f
#define LOG001   -4.605170185988091f   // log(0.01)
#define HALF_L2PI 0.9189385332046727f  // 0.5*log(2*pi)

typedef __attribute__((ext_vector_type(8))) short bf16x8;   // 8 bf16 in 4 VGPRs
typedef __attribute__((ext_vector_type(4))) float f32x4;

#define H_PITCH   520   // 512 + 8 bf16 pad (16B-aligned rows, breaks pow2 bank stride)
#define PHI_PITCH 264   // 256 + 8 bf16 pad

__device__ inline unsigned short f2bf(float f) {   // fp32 -> bf16 bits, RNE
    union { float f; unsigned u; } v; v.f = f;
    unsigned r = v.u + 0x7FFFu + ((v.u >> 16) & 1u);
    return (unsigned short)(r >> 16);
}

// ---------------- zero/init: hb16A=0, flags=0, out=0 ----------------
__global__ void zero_init(unsigned* __restrict__ hb16A_u32,
                          unsigned* __restrict__ flags, float* __restrict__ out) {
    int i = blockIdx.x * blockDim.x + threadIdx.x;
    if (i < B_SZ * H_SZ / 2) hb16A_u32[i] = 0u;
    if (i < 1024) flags[i] = 0u;
    if (i == 0) out[0] = 0.f;
}

// ---------------- pack W -> bf16: wpack[col][768] = [W_hh[col][0:512] | W_ih[col][0:256]] ----
// col = gate*512 + j, gate order r,z,n (torch GRUCell layout). K-contig rows = MFMA B^T layout.
__global__ void pack_w(const float* __restrict__ W_ih, const float* __restrict__ W_hh,
                       unsigned short* __restrict__ wpack) {
    const int n = 1536 * 768;
    for (int i = blockIdx.x * blockDim.x + threadIdx.x; i < n; i += gridDim.x * blockDim.x) {
        int col = i / 768, k = i - col * 768;
        float v = (k < H_SZ) ? W_hh[col * H_SZ + k] : W_ih[col * E_SZ + (k - H_SZ)];
        wpack[i] = f2bf(v);
    }
}

// ---------------- embed: phi_bf16[row][e] = bf16(relu(b_embed[e] + x[row]·W_embed[e])) -------
__global__ __launch_bounds__(256) void embed_phi(
    const float* __restrict__ x, const float* __restrict__ W_embed,
    const float* __restrict__ b_embed, unsigned short* __restrict__ phi) {
    __shared__ float xs[8][32];
    const int e = threadIdx.x;
    float w[MD];
    #pragma unroll
    for (int m = 0; m < MD; ++m) w[m] = W_embed[e * MD + m];
    const float be = b_embed[e];
    const int nblocks = (T_LEN * B_SZ) / 8;
    for (int rb = blockIdx.x; rb < nblocks; rb += gridDim.x) {
        const int r0 = rb * 8;
        if (threadIdx.x < 8 * MD)
            xs[threadIdx.x / MD][threadIdx.x % MD] = x[(size_t)r0 * MD + threadIdx.x];
        __syncthreads();
        #pragma unroll
        for (int i = 0; i < 8; ++i) {
            float acc = be;
            #pragma unroll
            for (int m = 0; m < MD; ++m) acc = fmaf(xs[i][m], w[m], acc);
            phi[(size_t)(r0 + i) * E_SZ + e] = f2bf(fmaxf(acc, 0.f));
        }
        __syncthreads();
    }
}

// ---------------- persistent GRU recurrence, latency-trimmed ---------------------------------
// grid 256 = 32 j-groups (ct) x 8 b-groups (bt). block 384 = 6 waves = (gate r,z,n) x (K-half).
// - fp32 h state lives in REGISTERS (each block re-reads only its own cells) -> only bf16
//   shadow crosses blocks (relaxed AGENT atomics, sc1 -> LLC = cross-XCD coherence point).
// - phi double-buffered in LDS; next step's slice prefetched during current MFMA (removes
//   per-step HBM miss from the barrier-to-barrier critical path).
// - barrier flags: one 128B line per bt-group (32 dwords), plain relaxed stores, 2-line poll.
__global__ __launch_bounds__(384) void gru_persist(
    const unsigned short* __restrict__ wpack, const unsigned short* __restrict__ phi,
    unsigned short* __restrict__ hb16A, unsigned short* __restrict__ hb16B,
    float* __restrict__ hs,
    const float* __restrict__ b_ih, const float* __restrict__ b_hh,
    unsigned* __restrict__ flags) {
    __shared__ __align__(16) short act_s[16 * H_PITCH];          // 16.6 KB h tile
    __shared__ __align__(16) short phi_s[2][16 * PHI_PITCH];     // 16.9 KB phi dbuf
    __shared__ float red_s[6][256];                              // 6 KB partial C tiles

    const int tid = threadIdx.x;
    const int bt = blockIdx.x & 7, ct = blockIdx.x >> 3;
    const int b0 = bt * 16, j0 = ct * 16;

    const int wid = tid >> 6, L = tid & 63;
    const int gt = wid >> 1, kh = wid & 1;
    const int n_loc = L & 15, kb = L >> 4;

    // --- preload loop-invariant B fragments into registers ---
    const unsigned short* __restrict__ wrow = wpack + (size_t)(gt * 512 + j0 + n_loc) * 768;
    const int k_beg = kh ? 512 : 0;
    bf16x8 Bf[16];
    #pragma unroll
    for (int i = 0; i < 16; ++i) {
        const int ii = kh ? (i & 7) : i;   // kh=1 has only 8 frags; duplicate harmlessly
        Bf[i] = *(const bf16x8*)(wrow + k_beg + ii * 32 + kb * 8);
    }

    // gate-phase invariants (threads 0..255: cell b = b0 + (tid>>4), j = j0 + (tid&15))
    const int gb = tid >> 4, gj = tid & 15;
    float bias_r = 0.f, bias_z = 0.f, bias_xn = 0.f, bias_hn = 0.f;
    if (tid < 256) {
        const int j = j0 + gj;
        bias_r  = b_ih[j] + b_hh[j];
        bias_z  = b_ih[512 + j] + b_hh[512 + j];
        bias_xn = b_ih[1024 + j];
        bias_hn = b_hh[1024 + j];
    }
    float hold = 0.f;   // register-resident fp32 state for this thread's (b,j) cell

    unsigned* __restrict__ flag_own  = flags + bt * 32 + ct;
    unsigned* __restrict__ flag_poll = flags + bt * 32 + (L & 31);

    // --- prefetch phi slice for t=0 into phi_s[0] (plain loads; phi is read-only) ---
    #pragma unroll
    for (int it = 0; it < 3; ++it) {
        const int c = tid + it * 384;
        if (c < 1024) {
            const int m = c >> 6, q = c & 63;
            *(unsigned long long*)(phi_s[0] + m * PHI_PITCH + q * 4) =
                *(const unsigned long long*)(phi + ((size_t)(b0 + m)) * E_SZ + q * 4);
        }
    }
    __syncthreads();

    for (int t = 0; t < T_LEN; ++t) {
        const unsigned short* hb_cur = (t & 1) ? hb16B : hb16A;
        unsigned short* hb_nxt       = (t & 1) ? hb16A : hb16B;
        const short* phi_cur         = phi_s[t & 1];

        // --- stage h tile: 16 rows x 512 bf16 = 2048 u64 chunks (LLC-coherent loads) ---
        #pragma unroll
        for (int it = 0; it < 6; ++it) {
            const int c = tid + it * 384;
            if (c < 2048) {
                const int m = c >> 7, q = c & 127;
                unsigned long long v = __hip_atomic_load(
                    (const unsigned long long*)(hb_cur + (size_t)(b0 + m) * H_SZ + q * 4),
                    __ATOMIC_RELAXED, __HIP_MEMORY_SCOPE_AGENT);
                *(unsigned long long*)(act_s + m * H_PITCH + q * 4) = v;
            }
        }
        __syncthreads();

        // --- phase A: issue next step's phi loads (held in regs across the MFMA) ---
        unsigned long long pv[3];
        const int tn = t + 1;
        if (tn < T_LEN) {
            #pragma unroll
            for (int it = 0; it < 3; ++it) {
                const int c = tid + it * 384;
                if (c < 1024) {
                    const int m = c >> 6, q = c & 63;
                    pv[it] = *(const unsigned long long*)(
                        phi + ((size_t)tn * B_SZ + b0 + m) * E_SZ + q * 4);
                }
            }
        }

        // --- phase B: MFMA from LDS(A) x VGPR(B) ---
        {
            f32x4 acc = {0.f, 0.f, 0.f, 0.f};
            if (kh == 0) {
                const short* arow = act_s + n_loc * H_PITCH + kb * 8;
                #pragma unroll
                for (int i = 0; i < 16; ++i) {
                    bf16x8 a = *(const bf16x8*)(arow + i * 32);
                    acc = __builtin_amdgcn_mfma_f32_16x16x32_bf16(a, Bf[i], acc, 0, 0, 0);
                }
            } else {
                const short* prow = phi_cur + n_loc * PHI_PITCH + kb * 8;
                #pragma unroll
                for (int i = 0; i < 8; ++i) {
                    bf16x8 a = *(const bf16x8*)(prow + i * 32);
                    acc = __builtin_amdgcn_mfma_f32_16x16x32_bf16(a, Bf[i], acc, 0, 0, 0);
                }
            }
            #pragma unroll
            for (int i = 0; i < 4; ++i)              // D: row=(L>>4)*4+i, col=L&15
                red_s[wid][(kb * 4 + i) * 16 + n_loc] = acc[i];
        }

        // --- phase C: commit prefetched phi to the other LDS buffer ---
        if (tn < T_LEN) {
            short* pbuf = phi_s[tn & 1];
            #pragma unroll
            for (int it = 0; it < 3; ++it) {
                const int c = tid + it * 384;
                if (c < 1024) {
                    const int m = c >> 6, q = c & 63;
                    *(unsigned long long*)(pbuf + m * PHI_PITCH + q * 4) = pv[it];
                }
            }
        }
        __syncthreads();   // red_s ready (phi_s[next] writes covered by later barriers)

        // --- gate math + state update (threads 0..255, one cell each) ---
        if (tid < 256) {
            const int cell = gb * 16 + gj;
            const int b = b0 + gb, j = j0 + gj;
            const float pre_r = red_s[0][cell] + red_s[1][cell] + bias_r;
            const float pre_z = red_s[2][cell] + red_s[3][cell] + bias_z;
            const float hn    = red_s[4][cell] + bias_hn;   // h-part of n gate
            const float xn    = red_s[5][cell] + bias_xn;   // phi-part of n gate
            const float r = 1.f / (1.f + expf(-pre_r));
            const float z = 1.f / (1.f + expf(-pre_z));
            const float n = tanhf(fmaf(r, hn, xn));
            const float hnew = fmaf(z, hold - n, n);        // (1-z)*n + z*h
            hold = hnew;                                     // register state update
            // pack 2 adjacent cells into one u32 LLC store (gj even lane stores)
            const unsigned short myb = f2bf(hnew);
            const unsigned other = (unsigned)(unsigned short)__shfl_xor((int)(unsigned)myb, 1);
            if ((gj & 1) == 0)
                __hip_atomic_store(
                    (unsigned*)(hb_nxt + (size_t)b * H_SZ + j),
                    (unsigned)myb | (other << 16),
                    __ATOMIC_RELAXED, __HIP_MEMORY_SCOPE_AGENT);
            if (t < T_LEN - 1)                               // hs[t+1] = state after step t
                hs[(size_t)(t + 1) * B_SZ * H_SZ + (size_t)b * H_SZ + j] = hnew;
        }
        if (t == T_LEN - 1) break;       // no consumer of the last exchange
        __syncthreads();                 // drains every wave's sc1 stores (vmcnt(0))

        // --- bt-group barrier: packed monotonic flags (one 128B line), 2-line poll ---
        if (tid == 0)
            __hip_atomic_store(flag_own, (unsigned)(t + 1),
                               __ATOMIC_RELAXED, __HIP_MEMORY_SCOPE_AGENT);
        if (wid == 0) {
            const unsigned tgt = (unsigned)(t + 1);
            while (true) {
                unsigned v = __hip_atomic_load(flag_poll, __ATOMIC_RELAXED,
                                               __HIP_MEMORY_SCOPE_AGENT);
                if (__ballot(v >= tgt) == ~0ull) break;
                __builtin_amdgcn_s_sleep(2);
            }
        }
        __syncthreads();
    }
}

// ---------------- he + mu/logvar + loss, fused (unchanged, proven) --------------------------
__global__ __launch_bounds__(256) void he_loss(
    const float* __restrict__ hs, const float* __restrict__ W_he, const float* __restrict__ b_he,
    const float* __restrict__ W_mu, const float* __restrict__ b_mu,
    const float* __restrict__ W_lv, const float* __restrict__ b_lv,
    const float* __restrict__ h_inf, const float* __restrict__ time_inf,
    const float* __restrict__ base_int, const float* __restrict__ x,
    const float* __restrict__ t_in, const float* __restrict__ mask,
    float* __restrict__ out) {
    __shared__ float he_s[16][129];
    __shared__ float wmu_s[MD][129];
    __shared__ float wlv_s[MD][129];
    __shared__ float hinf_s[S_SZ];
    __shared__ float red[4];
    for (int i = threadIdx.x; i < MD * S_SZ; i += 256) {
        wmu_s[i / S_SZ][i % S_SZ] = W_mu[i];
        wlv_s[i / S_SZ][i % S_SZ] = W_lv[i];
    }
    if (threadIdx.x < S_SZ) hinf_s[threadIdx.x] = h_inf[threadIdx.x];
    __syncthreads();

    const int row0 = B_SZ + blockIdx.x * 16;   // skip t=0 rows
    {
        const int c = threadIdx.x & 127, rg = threadIdx.x >> 7;
        const float* __restrict__ wrow = W_he + (size_t)c * H_SZ;
        float acc[8];
        #pragma unroll
        for (int i = 0; i < 8; ++i) acc[i] = b_he[c];
        for (int k = 0; k < H_SZ; k += 4) {
            const float4 w4 = *(const float4*)(wrow + k);
            #pragma unroll
            for (int i = 0; i < 8; ++i) {
                const float4 h4 = *(const float4*)(hs + (size_t)(row0 + rg * 8 + i) * H_SZ + k);
                acc[i] = fmaf(w4.x, h4.x, acc[i]);
                acc[i] = fmaf(w4.y, h4.y, acc[i]);
                acc[i] = fmaf(w4.z, h4.z, acc[i]);
                acc[i] = fmaf(w4.w, h4.w, acc[i]);
            }
        }
        #pragma unroll
        for (int i = 0; i < 8; ++i) he_s[rg * 8 + i][c] = fmaxf(acc[i], 0.f);
    }
    __syncthreads();
    const int r = threadIdx.x >> 4, q = threadIdx.x & 15;
    const int row = row0 + r;
    const float mk = mask[row];
    float lacc = 0.f;
    #pragma unroll
    for (int pass = 0; pass < 2; ++pass) {
        const int m = q + pass * 16;
        if (m < MD) {
            float mu = b_mu[m], lv = b_lv[m];
            for (int c2 = 0; c2 < S_SZ; ++c2) {
                const float h = he_s[r][c2];
                mu = fmaf(h, wmu_s[m][c2], mu);
                lv = fmaf(h, wlv_s[m][c2], lv);
            }
            const float ls    = fmaxf(0.5f * lv, LOG001);
            const float inv_s = expf(-ls);
            const float zz    = (x[(size_t)row * MD + m] - mu) * inv_s;
            lacc += (0.5f * zz * zz + ls + HALF_L2PI) * mk;
        }
    }
    if (q == 0) {
        float past = 0.f;
        for (int c2 = 0; c2 < S_SZ; ++c2) past = fmaf(he_s[r][c2], hinf_s[c2], past);
        const float ti = time_inf[0], bi = base_int[0];
        const float dt = t_in[(size_t)row * 2 + 1];
        const float term1 = past + ti * dt + bi;
        const float tll = term1 + (expf(past + bi) - expf(term1)) / ti;
        lacc += GAMMA_F * (-tll) * mk;
    }
    #pragma unroll
    for (int off = 32; off > 0; off >>= 1) lacc += __shfl_down(lacc, off, 64);
    if ((threadIdx.x & 63) == 0) red[threadIdx.x >> 6] = lacc;
    __syncthreads();
    if (threadIdx.x == 0) atomicAdd(out, red[0] + red[1] + red[2] + red[3]);
}

extern "C" void kernel_launch(void* const* d_in, const int* in_sizes, int n_in,
                              void* d_out, int out_size, void* d_ws, size_t ws_size,
                              hipStream_t stream) {
    const float* x       = (const float*)d_in[0];
    const float* t_in    = (const float*)d_in[1];
    const float* mask    = (const float*)d_in[2];
    const float* W_embed = (const float*)d_in[3];
    const float* b_embed = (const float*)d_in[4];
    const float* W_ih    = (const float*)d_in[5];
    const float* b_ih    = (const float*)d_in[6];
    const float* W_hh    = (const float*)d_in[7];
    const float* b_hh    = (const float*)d_in[8];
    const float* W_he    = (const float*)d_in[9];
    const float* b_he    = (const float*)d_in[10];
    const float* W_mu    = (const float*)d_in[11];
    const float* b_mu    = (const float*)d_in[12];
    const float* W_lv    = (const float*)d_in[13];
    const float* b_lv    = (const float*)d_in[14];
    const float* h_inf   = (const float*)d_in[15];
    const float* tinf    = (const float*)d_in[16];
    const float* bint    = (const float*)d_in[17];
    float* out = (float*)d_out;

    // ws layout (bytes), 256-aligned:
    // phi_bf16 33.5M | hs fp32 134.2M | wpack_bf16 2.36M | hb16 A/B 128K each | flags 4K
    char* ws = (char*)d_ws;
    const size_t OFF_PHI   = 0;
    const size_t OFF_HS    = 33554432ull;
    const size_t OFF_WP    = 167772160ull;
    const size_t OFF_HB16A = 170131456ull;
    const size_t OFF_HB16B = 170262528ull;
    const size_t OFF_FLAGS = 170393600ull;
    const size_t TOTAL     = 170397696ull;
    if (ws_size < TOTAL) return;
    unsigned short* phi   = (unsigned short*)(ws + OFF_PHI);
    float*          hsbuf = (float*)(ws + OFF_HS);
    unsigned short* wpack = (unsigned short*)(ws + OFF_WP);
    unsigned short* hb16A = (unsigned short*)(ws + OFF_HB16A);
    unsigned short* hb16B = (unsigned short*)(ws + OFF_HB16B);
    unsigned*       flags = (unsigned*)(ws + OFF_FLAGS);

    zero_init<<<dim3(128), 256, 0, stream>>>((unsigned*)hb16A, flags, out);
    pack_w<<<dim3(512), 256, 0, stream>>>(W_ih, W_hh, wpack);
    embed_phi<<<dim3(1024), 256, 0, stream>>>(x, W_embed, b_embed, phi);

    void* args[] = {(void*)&wpack, (void*)&phi, (void*)&hb16A, (void*)&hb16B,
                    (void*)&hsbuf, (void*)&b_ih, (void*)&b_hh, (void*)&flags};
    hipLaunchCooperativeKernel((void*)gru_persist, dim3(256), dim3(384), args, 0, stream);

    he_loss<<<dim3((T_LEN - 1) * B_SZ / 16), 256, 0, stream>>>(
        hsbuf, W_he, b_he, W_mu, b_mu, W_lv, b_lv, h_inf, tinf, bint, x, t_in, mask, out);
}

// Round 6
// 2394.733 us; speedup vs baseline: 20.5245x; 1.1168x over previous
//
#include <hip/hip_runtime.h>
#include <cstddef>
#include <cstdint>

// Model dims (fixed by reference)
#define T_LEN 512
#define B_SZ  128
#define MD    31
#define E_SZ  256
#define H_SZ  512
#define S_SZ  128
#define GAMMA_F 1.0f
#define LOG001   -4.605170185988091f   // log(0.01)
#define HALF_L2PI 0.9189385332046727f  // 0.5*log(2*pi)

typedef __attribute__((ext_vector_type(8))) short bf16x8;   // 8 bf16 in 4 VGPRs
typedef __attribute__((ext_vector_type(4))) float f32x4;

#define ACT_PITCH 536   // shorts: 512 + 24 pad; 1072B row = 16B-aligned, 2-way max bank alias
#define PHI_PITCH 264   // shorts: 256 + 8 pad; 528B = 16B-aligned
#define GP        36    // gate-array col pitch (floats)

__device__ inline unsigned short f2bf(float f) {   // fp32 -> bf16 bits, RNE
    union { float f; unsigned u; } v; v.f = f;
    unsigned r = v.u + 0x7FFFu + ((v.u >> 16) & 1u);
    return (unsigned short)(r >> 16);
}
__device__ inline unsigned long long llc_load_u64(const unsigned long long* p) {
    return __hip_atomic_load(p, __ATOMIC_RELAXED, __HIP_MEMORY_SCOPE_AGENT);
}

// ---------------- zero/init: hx buf0 = 0 (tag 0 == step 0, h=0), out = 0 ----------------
__global__ void zero_init(unsigned* __restrict__ hx, float* __restrict__ out) {
    int i = blockIdx.x * blockDim.x + threadIdx.x;
    if (i < 65536) hx[i] = 0u;   // buf0: 8 bt x 16 ct x 512 u32
    if (i == 0) out[0] = 0.f;
}

// ---------------- pack W -> bf16: wpack[col][768] = [W_hh[col][0:512] | W_ih[col][0:256]] ----
// col = gate*512 + j, gate order r,z,n (torch GRUCell layout). K-contig rows = MFMA B^T layout.
__global__ void pack_w(const float* __restrict__ W_ih, const float* __restrict__ W_hh,
                       unsigned short* __restrict__ wpack) {
    const int n = 1536 * 768;
    for (int i = blockIdx.x * blockDim.x + threadIdx.x; i < n; i += gridDim.x * blockDim.x) {
        int col = i / 768, k = i - col * 768;
        float v = (k < H_SZ) ? W_hh[col * H_SZ + k] : W_ih[col * E_SZ + (k - H_SZ)];
        wpack[i] = f2bf(v);
    }
}

// ---------------- embed: phi_bf16[row][e] = bf16(relu(b_embed[e] + x[row]·W_embed[e])) -------
__global__ __launch_bounds__(256) void embed_phi(
    const float* __restrict__ x, const float* __restrict__ W_embed,
    const float* __restrict__ b_embed, unsigned short* __restrict__ phi) {
    __shared__ float xs[8][32];
    const int e = threadIdx.x;
    float w[MD];
    #pragma unroll
    for (int m = 0; m < MD; ++m) w[m] = W_embed[e * MD + m];
    const float be = b_embed[e];
    const int nblocks = (T_LEN * B_SZ) / 8;
    for (int rb = blockIdx.x; rb < nblocks; rb += gridDim.x) {
        const int r0 = rb * 8;
        if (threadIdx.x < 8 * MD)
            xs[threadIdx.x / MD][threadIdx.x % MD] = x[(size_t)r0 * MD + threadIdx.x];
        __syncthreads();
        #pragma unroll
        for (int i = 0; i < 8; ++i) {
            float acc = be;
            #pragma unroll
            for (int m = 0; m < MD; ++m) acc = fmaf(xs[i][m], w[m], acc);
            phi[(size_t)(r0 + i) * E_SZ + e] = f2bf(fmaxf(acc, 0.f));
        }
        __syncthreads();
    }
}

// ---------------- persistent GRU recurrence, self-synchronizing via tagged data --------------
// grid 128 = 16 j-groups (ct) x 8 b-groups (bt). block 384 = 6 waves = (gate r,z,n) x col-half.
// Exchange word: u32 = (bf16(h)<<16) | (step & 0xFFFF). Staging polls tags -> barrier == data
// arrival; no flags, no fences, no drains. Double-buffered hx (step parity); safety from the
// data dependency (writing t+2 requires having consumed t+1). fp32 h in registers.
__global__ __launch_bounds__(384) void gru_persist(
    const unsigned short* __restrict__ wpack, const unsigned short* __restrict__ phi,
    unsigned* __restrict__ hx, float* __restrict__ hs,
    const float* __restrict__ b_ih, const float* __restrict__ b_hh) {
    __shared__ __align__(16) short act_s[16 * ACT_PITCH];        // 17.2 KB h tile (bf16)
    __shared__ __align__(16) short phi_s[2][16 * PHI_PITCH];     // 16.9 KB phi dbuf
    __shared__ float g_s[4][16 * GP];                            // pre_r, pre_z, hn, xn

    const int tid = threadIdx.x;
    const int bt = blockIdx.x & 7, ct = blockIdx.x >> 3;
    const int b0 = bt * 16, j0 = ct * 32;

    const int wid = tid >> 6, L = tid & 63;
    const int gt = wid >> 1, ch = wid & 1;           // gate 0=r,1=z,2=n; col-half
    const int n_loc = L & 15, kb2 = L >> 4;
    const int a_row = L & 15;

    // --- preload loop-invariant B fragments: 24 k-blocks x bf16x8 = 96 VGPRs ---
    const unsigned short* __restrict__ wrow =
        wpack + (size_t)(gt * 512 + j0 + ch * 16 + n_loc) * 768;
    bf16x8 Bf[24];
    #pragma unroll
    for (int i = 0; i < 24; ++i) Bf[i] = *(const bf16x8*)(wrow + i * 32 + kb2 * 8);

    // gate-phase invariants: thread tid<256 handles cells (row, col) and (row+8, col)
    const int g_row = tid >> 5, g_col = tid & 31;    // row 0..7, col 0..31
    float bias_r = 0.f, bias_z = 0.f, bias_xn = 0.f, bias_hn = 0.f;
    if (tid < 256) {
        const int j = j0 + g_col;
        bias_r  = b_ih[j] + b_hh[j];
        bias_z  = b_ih[512 + j] + b_hh[512 + j];
        bias_xn = b_ih[1024 + j];
        bias_hn = b_hh[1024 + j];
    }
    float hold1 = 0.f, hold2 = 0.f;                  // fp32 state, cells (g_row,c) (g_row+8,c)

    // --- prefetch phi slice for t=0 (16 rows x 256 bf16 = 1024 u64, 3/thread) ---
    #pragma unroll
    for (int it = 0; it < 3; ++it) {
        const int c = tid + it * 384;
        if (c < 1024) {
            const int m = c >> 6, q = c & 63;
            *(unsigned long long*)(phi_s[0] + m * PHI_PITCH + q * 4) =
                *(const unsigned long long*)(phi + ((size_t)(b0 + m)) * E_SZ + q * 4);
        }
    }

    for (int t = 0; t < T_LEN - 1; ++t) {            // step 511 would produce unused h_512
        const int buf = t & 1;
        const short* phi_cur = phi_s[buf];
        const unsigned tg = (unsigned)t & 0xFFFFu;

        // --- staging + implicit barrier: poll 4096 tagged u64 words of h_t ---
        // consumer word c maps contiguously: hx64base + c  (chunks are producer-contiguous)
        const unsigned long long* hx64 =
            (const unsigned long long*)hx + ((size_t)(buf * 8 + bt)) * 4096;
        unsigned long long v[11];
        #pragma unroll
        for (int it = 0; it < 11; ++it) {
            const int c = tid + it * 384;
            if (c < 4096) v[it] = llc_load_u64(hx64 + c);
        }
        while (true) {
            unsigned bad = 0;
            #pragma unroll
            for (int it = 0; it < 11; ++it) {
                const int c = tid + it * 384;
                if (c < 4096) {
                    const unsigned t0 = (unsigned)v[it] & 0xFFFFu;
                    const unsigned t1 = (unsigned)(v[it] >> 32) & 0xFFFFu;
                    if ((t0 ^ tg) | (t1 ^ tg)) bad |= (1u << it);
                }
            }
            if (bad == 0) break;
            #pragma unroll
            for (int it = 0; it < 11; ++it)
                if (bad & (1u << it)) v[it] = llc_load_u64(hx64 + tid + it * 384);
        }
        #pragma unroll
        for (int it = 0; it < 11; ++it) {            // commit bf16 pairs to LDS
            const int c = tid + it * 384;
            if (c < 4096) {
                const int ctp = c >> 8, w = c & 255, row = w >> 4, colp = w & 15;
                const unsigned lo = (unsigned)(v[it] >> 16) & 0xFFFFu;
                const unsigned hi = (unsigned)(v[it] >> 48) & 0xFFFFu;
                *(unsigned*)(act_s + row * ACT_PITCH + ctp * 32 + colp * 2) = lo | (hi << 16);
            }
        }
        __syncthreads();

        // --- issue next phi prefetch (regs across MFMA) ---
        unsigned long long pv[3];
        const int tn = t + 1;
        if (tn < T_LEN - 1) {
            #pragma unroll
            for (int it = 0; it < 3; ++it) {
                const int c = tid + it * 384;
                if (c < 1024) {
                    const int m = c >> 6, q = c & 63;
                    pv[it] = *(const unsigned long long*)(
                        phi + ((size_t)tn * B_SZ + b0 + m) * E_SZ + q * 4);
                }
            }
        }

        // --- MFMA: one wave per (gate, col-half), full K=768, n-gate keeps h/phi split ---
        {
            const short* arow = act_s + a_row * ACT_PITCH;
            const short* prow = phi_cur + a_row * PHI_PITCH;
            f32x4 accA = {0.f, 0.f, 0.f, 0.f};
            f32x4 accB = {0.f, 0.f, 0.f, 0.f};
            #pragma unroll
            for (int i = 0; i < 16; ++i) {           // h part k in [0,512)
                bf16x8 a = *(const bf16x8*)(arow + i * 32 + kb2 * 8);
                accA = __builtin_amdgcn_mfma_f32_16x16x32_bf16(a, Bf[i], accA, 0, 0, 0);
            }
            if (gt < 2) {
                #pragma unroll
                for (int i = 16; i < 24; ++i) {      // phi part merges into same acc
                    bf16x8 a = *(const bf16x8*)(prow + (i - 16) * 32 + kb2 * 8);
                    accA = __builtin_amdgcn_mfma_f32_16x16x32_bf16(a, Bf[i], accA, 0, 0, 0);
                }
                #pragma unroll
                for (int i2 = 0; i2 < 4; ++i2)       // D: row=(L>>4)*4+i2, col=L&15
                    g_s[gt][((L >> 4) * 4 + i2) * GP + ch * 16 + n_loc] = accA[i2];
            } else {
                #pragma unroll
                for (int i = 16; i < 24; ++i) {      // n-gate phi part separate
                    bf16x8 a = *(const bf16x8*)(prow + (i - 16) * 32 + kb2 * 8);
                    accB = __builtin_amdgcn_mfma_f32_16x16x32_bf16(a, Bf[i], accB, 0, 0, 0);
                }
                #pragma unroll
                for (int i2 = 0; i2 < 4; ++i2) {
                    const int idx = ((L >> 4) * 4 + i2) * GP + ch * 16 + n_loc;
                    g_s[2][idx] = accA[i2];          // hn
                    g_s[3][idx] = accB[i2];          // xn
                }
            }
        }

        // --- commit prefetched phi to the other LDS buffer ---
        if (tn < T_LEN - 1) {
            short* pbuf = phi_s[tn & 1];
            #pragma unroll
            for (int it = 0; it < 3; ++it) {
                const int c = tid + it * 384;
                if (c < 1024) {
                    const int m = c >> 6, q = c & 63;
                    *(unsigned long long*)(pbuf + m * PHI_PITCH + q * 4) = pv[it];
                }
            }
        }
        __syncthreads();

        // --- gate math + state update + tagged store (2 cells per thread, tid<256) ---
        if (tid < 256) {
            const int nb = (t + 1) & 1;
            unsigned* hxdst = hx + ((size_t)(nb * 8 + bt) * 16 + ct) * 512;
            #pragma unroll
            for (int half = 0; half < 2; ++half) {
                const int row = g_row + half * 8;
                const int idx = row * GP + g_col;
                float& hold = half ? hold2 : hold1;
                const float pre_r = g_s[0][idx] + bias_r;
                const float pre_z = g_s[1][idx] + bias_z;
                const float hn    = g_s[2][idx] + bias_hn;
                const float xn    = g_s[3][idx] + bias_xn;
                const float r = 1.f / (1.f + __expf(-pre_r));
                const float z = 1.f / (1.f + __expf(-pre_z));
                const float e2 = __expf(-2.f * fmaf(r, hn, xn));
                const float n = (1.f - e2) / (1.f + e2);          // tanh
                const float hnew = fmaf(z, hold - n, n);          // (1-z)*n + z*h
                hold = hnew;
                hs[(size_t)(t + 1) * B_SZ * H_SZ + (size_t)(b0 + row) * H_SZ + j0 + g_col] = hnew;
                if (t < T_LEN - 2)                    // last consumed state is h_{510}
                    __hip_atomic_store(hxdst + row * 32 + g_col,
                                       ((unsigned)f2bf(hnew) << 16) | ((unsigned)(t + 1) & 0xFFFFu),
                                       __ATOMIC_RELAXED, __HIP_MEMORY_SCOPE_AGENT);
            }
        }
        // no barrier needed here: next staging writes act_s only after this thread's gates;
        // g_s next-write is fenced by next iteration's first __syncthreads
    }
}

// ---------------- he + mu/logvar + loss, fused (unchanged, proven) --------------------------
__global__ __launch_bounds__(256) void he_loss(
    const float* __restrict__ hs, const float* __restrict__ W_he, const float* __restrict__ b_he,
    const float* __restrict__ W_mu, const float* __restrict__ b_mu,
    const float* __restrict__ W_lv, const float* __restrict__ b_lv,
    const float* __restrict__ h_inf, const float* __restrict__ time_inf,
    const float* __restrict__ base_int, const float* __restrict__ x,
    const float* __restrict__ t_in, const float* __restrict__ mask,
    float* __restrict__ out) {
    __shared__ float he_s[16][129];
    __shared__ float wmu_s[MD][129];
    __shared__ float wlv_s[MD][129];
    __shared__ float hinf_s[S_SZ];
    __shared__ float red[4];
    for (int i = threadIdx.x; i < MD * S_SZ; i += 256) {
        wmu_s[i / S_SZ][i % S_SZ] = W_mu[i];
        wlv_s[i / S_SZ][i % S_SZ] = W_lv[i];
    }
    if (threadIdx.x < S_SZ) hinf_s[threadIdx.x] = h_inf[threadIdx.x];
    __syncthreads();

    const int row0 = B_SZ + blockIdx.x * 16;   // skip t=0 rows
    {
        const int c = threadIdx.x & 127, rg = threadIdx.x >> 7;
        const float* __restrict__ wrow = W_he + (size_t)c * H_SZ;
        float acc[8];
        #pragma unroll
        for (int i = 0; i < 8; ++i) acc[i] = b_he[c];
        for (int k = 0; k < H_SZ; k += 4) {
            const float4 w4 = *(const float4*)(wrow + k);
            #pragma unroll
            for (int i = 0; i < 8; ++i) {
                const float4 h4 = *(const float4*)(hs + (size_t)(row0 + rg * 8 + i) * H_SZ + k);
                acc[i] = fmaf(w4.x, h4.x, acc[i]);
                acc[i] = fmaf(w4.y, h4.y, acc[i]);
                acc[i] = fmaf(w4.z, h4.z, acc[i]);
                acc[i] = fmaf(w4.w, h4.w, acc[i]);
            }
        }
        #pragma unroll
        for (int i = 0; i < 8; ++i) he_s[rg * 8 + i][c] = fmaxf(acc[i], 0.f);
    }
    __syncthreads();
    const int r = threadIdx.x >> 4, q = threadIdx.x & 15;
    const int row = row0 + r;
    const float mk = mask[row];
    float lacc = 0.f;
    #pragma unroll
    for (int pass = 0; pass < 2; ++pass) {
        const int m = q + pass * 16;
        if (m < MD) {
            float mu = b_mu[m], lv = b_lv[m];
            for (int c2 = 0; c2 < S_SZ; ++c2) {
                const float h = he_s[r][c2];
                mu = fmaf(h, wmu_s[m][c2], mu);
                lv = fmaf(h, wlv_s[m][c2], lv);
            }
            const float ls    = fmaxf(0.5f * lv, LOG001);
            const float inv_s = expf(-ls);
            const float zz    = (x[(size_t)row * MD + m] - mu) * inv_s;
            lacc += (0.5f * zz * zz + ls + HALF_L2PI) * mk;
        }
    }
    if (q == 0) {
        float past = 0.f;
        for (int c2 = 0; c2 < S_SZ; ++c2) past = fmaf(he_s[r][c2], hinf_s[c2], past);
        const float ti = time_inf[0], bi = base_int[0];
        const float dt = t_in[(size_t)row * 2 + 1];
        const float term1 = past + ti * dt + bi;
        const float tll = term1 + (expf(past + bi) - expf(term1)) / ti;
        lacc += GAMMA_F * (-tll) * mk;
    }
    #pragma unroll
    for (int off = 32; off > 0; off >>= 1) lacc += __shfl_down(lacc, off, 64);
    if ((threadIdx.x & 63) == 0) red[threadIdx.x >> 6] = lacc;
    __syncthreads();
    if (threadIdx.x == 0) atomicAdd(out, red[0] + red[1] + red[2] + red[3]);
}

extern "C" void kernel_launch(void* const* d_in, const int* in_sizes, int n_in,
                              void* d_out, int out_size, void* d_ws, size_t ws_size,
                              hipStream_t stream) {
    const float* x       = (const float*)d_in[0];
    const float* t_in    = (const float*)d_in[1];
    const float* mask    = (const float*)d_in[2];
    const float* W_embed = (const float*)d_in[3];
    const float* b_embed = (const float*)d_in[4];
    const float* W_ih    = (const float*)d_in[5];
    const float* b_ih    = (const float*)d_in[6];
    const float* W_hh    = (const float*)d_in[7];
    const float* b_hh    = (const float*)d_in[8];
    const float* W_he    = (const float*)d_in[9];
    const float* b_he    = (const float*)d_in[10];
    const float* W_mu    = (const float*)d_in[11];
    const float* b_mu    = (const float*)d_in[12];
    const float* W_lv    = (const float*)d_in[13];
    const float* b_lv    = (const float*)d_in[14];
    const float* h_inf   = (const float*)d_in[15];
    const float* tinf    = (const float*)d_in[16];
    const float* bint    = (const float*)d_in[17];
    float* out = (float*)d_out;

    // ws layout (bytes), 256-aligned:
    // phi_bf16 33.5M | hs fp32 134.2M | wpack_bf16 2.36M | hx 512K (2 bufs x 8 x 16 x 2KB)
    char* ws = (char*)d_ws;
    const size_t OFF_PHI = 0;
    const size_t OFF_HS  = 33554432ull;
    const size_t OFF_WP  = 167772160ull;
    const size_t OFF_HX  = 170131456ull;
    const size_t TOTAL   = 170655744ull;
    if (ws_size < TOTAL) return;
    unsigned short* phi   = (unsigned short*)(ws + OFF_PHI);
    float*          hsbuf = (float*)(ws + OFF_HS);
    unsigned short* wpack = (unsigned short*)(ws + OFF_WP);
    unsigned*       hx    = (unsigned*)(ws + OFF_HX);

    zero_init<<<dim3(256), 256, 0, stream>>>(hx, out);
    pack_w<<<dim3(512), 256, 0, stream>>>(W_ih, W_hh, wpack);
    embed_phi<<<dim3(1024), 256, 0, stream>>>(x, W_embed, b_embed, phi);

    void* args[] = {(void*)&wpack, (void*)&phi, (void*)&hx, (void*)&hsbuf,
                    (void*)&b_ih, (void*)&b_hh};
    hipLaunchCooperativeKernel((void*)gru_persist, dim3(128), dim3(384), args, 0, stream);

    he_loss<<<dim3((T_LEN - 1) * B_SZ / 16), 256, 0, stream>>>(
        hsbuf, W_he, b_he, W_mu, b_mu, W_lv, b_lv, h_inf, tinf, bint, x, t_in, mask, out);
}

// Round 7
// 2106.098 us; speedup vs baseline: 23.3373x; 1.1370x over previous
//
#include <hip/hip_runtime.h>
#include <cstddef>
#include <cstdint>

// Model dims (fixed by reference)
#define T_LEN 512
#define B_SZ  128
#define MD    31
#define E_SZ  256
#define H_SZ  512
#define S_SZ  128
#define GAMMA_F 1.0f
#define LOG001   -4.605170185988091f   // log(0.01)
#define HALF_L2PI 0.9189385332046727f  // 0.5*log(2*pi)

typedef __attribute__((ext_vector_type(8))) short bf16x8;   // 8 bf16 in 4 VGPRs
typedef __attribute__((ext_vector_type(4))) float f32x4;

#define ACT_PITCH 536   // shorts: 512 + 24 pad
#define PHI_PITCH 264   // shorts: 256 + 8 pad
#define GP        36    // gate-array col pitch (floats)
#define HS_PITCH  516   // loss hs tile pitch (floats)
#define WM_PITCH  132   // loss wmu/wlv pitch (ushorts)

// ---- shared-memory union (max of recurrence 43.3KB / loss 58.2KB) ----
#define SMEM_BYTES 58240
// recurrence offsets
#define R_ACT  0
#define R_PHI  17152
#define R_GS   34048
// loss offsets
#define L_HST  0
#define L_HES  33024
#define L_WMU  41280
#define L_WLV  49464
#define L_HINF 57648
#define L_RED  58176   // reuse: put red in first bytes of L_HES region instead
// (red stored at L_HINF+512 = 58160..58176; SMEM covers it)

__device__ inline unsigned short f2bf(float f) {   // fp32 -> bf16 bits, RNE
    union { float f; unsigned u; } v; v.f = f;
    unsigned r = v.u + 0x7FFFu + ((v.u >> 16) & 1u);
    return (unsigned short)(r >> 16);
}
__device__ inline float bf2f(unsigned short u) {
    union { unsigned u; float f; } v; v.u = (unsigned)u << 16; return v.f;
}
__device__ inline unsigned long long llc_load_u64(const unsigned long long* p) {
    return __hip_atomic_load(p, __ATOMIC_RELAXED, __HIP_MEMORY_SCOPE_AGENT);
}
__device__ inline unsigned llc_load_u32(const unsigned* p) {
    return __hip_atomic_load(p, __ATOMIC_RELAXED, __HIP_MEMORY_SCOPE_AGENT);
}

// ---------------- zero/init: hx buf0 = 0 (tag0 + h=0), counters = 0, out = 0 -----------------
__global__ void zero_init(unsigned* __restrict__ hx, unsigned* __restrict__ cnt,
                          float* __restrict__ out) {
    int i = blockIdx.x * blockDim.x + threadIdx.x;
    if (i < 65536) hx[i] = 0u;   // buf0: 8 bt x 16 ct x 512 u32
    if (i < 128) cnt[i] = 0u;
    if (i == 0) out[0] = 0.f;
}

// ---------------- pack W -> bf16: wpack[col][768] = [W_hh[col][0:512] | W_ih[col][0:256]] ----
__global__ void pack_w(const float* __restrict__ W_ih, const float* __restrict__ W_hh,
                       unsigned short* __restrict__ wpack) {
    const int n = 1536 * 768;
    for (int i = blockIdx.x * blockDim.x + threadIdx.x; i < n; i += gridDim.x * blockDim.x) {
        int col = i / 768, k = i - col * 768;
        float v = (k < H_SZ) ? W_hh[col * H_SZ + k] : W_ih[col * E_SZ + (k - H_SZ)];
        wpack[i] = f2bf(v);
    }
}

// ---------------- embed: phi_bf16[row][e] = bf16(relu(b_embed[e] + x[row]·W_embed[e])) -------
__global__ __launch_bounds__(256) void embed_phi(
    const float* __restrict__ x, const float* __restrict__ W_embed,
    const float* __restrict__ b_embed, unsigned short* __restrict__ phi) {
    __shared__ float xs[8][32];
    const int e = threadIdx.x;
    float w[MD];
    #pragma unroll
    for (int m = 0; m < MD; ++m) w[m] = W_embed[e * MD + m];
    const float be = b_embed[e];
    const int nblocks = (T_LEN * B_SZ) / 8;
    for (int rb = blockIdx.x; rb < nblocks; rb += gridDim.x) {
        const int r0 = rb * 8;
        if (threadIdx.x < 8 * MD)
            xs[threadIdx.x / MD][threadIdx.x % MD] = x[(size_t)r0 * MD + threadIdx.x];
        __syncthreads();
        #pragma unroll
        for (int i = 0; i < 8; ++i) {
            float acc = be;
            #pragma unroll
            for (int m = 0; m < MD; ++m) acc = fmaf(xs[i][m], w[m], acc);
            phi[(size_t)(r0 + i) * E_SZ + e] = f2bf(fmaxf(acc, 0.f));
        }
        __syncthreads();
    }
}

// ---------------- fused persistent kernel: 128 recurrence blocks + 128 loss blocks ----------
// Recurrence (blk<128): grid 16 ct x 8 bt, self-sync via tagged hx words (R6 scheme).
//   Publishes per-block step counter (safe: placed after a __syncthreads whose vmcnt(0)
//   drain already pushed the step's sc1 hs stores to LLC).
// Loss (blk>=128): consumes hs tiles (t, b-group) as counters permit; computes
//   he=relu(W_he.h) + mu/lv Gaussian LL + RMTPP time LL; one atomicAdd per block at end.
__global__ __launch_bounds__(384) void fused_persist(
    const unsigned short* __restrict__ wpack, const unsigned short* __restrict__ phi,
    unsigned* __restrict__ hx, float* __restrict__ hs,
    const float* __restrict__ b_ih, const float* __restrict__ b_hh,
    unsigned* __restrict__ cnt,
    const float* __restrict__ W_he, const float* __restrict__ b_he,
    const float* __restrict__ W_mu, const float* __restrict__ b_mu,
    const float* __restrict__ W_lv, const float* __restrict__ b_lv,
    const float* __restrict__ h_inf, const float* __restrict__ time_inf,
    const float* __restrict__ base_int, const float* __restrict__ x,
    const float* __restrict__ t_in, const float* __restrict__ mask,
    float* __restrict__ out) {
    __shared__ __align__(16) char smem[SMEM_BYTES];
    const int tid = threadIdx.x;

    if (blockIdx.x < 128) {
        // ================= RECURRENCE PATH =================
        short* act_s = (short*)(smem + R_ACT);
        short* phi_s0 = (short*)(smem + R_PHI);
        short* phi_s1 = (short*)(smem + R_PHI) + 16 * PHI_PITCH;
        float* g_s = (float*)(smem + R_GS);     // [4][16*GP]

        const int bt = blockIdx.x & 7, ct = blockIdx.x >> 3;
        const int b0 = bt * 16, j0 = ct * 32;
        const int wid = tid >> 6, L = tid & 63;
        const int gt = wid >> 1, ch = wid & 1;
        const int n_loc = L & 15, kb2 = L >> 4;
        const int a_row = L & 15;

        const unsigned short* __restrict__ wrow =
            wpack + (size_t)(gt * 512 + j0 + ch * 16 + n_loc) * 768;
        bf16x8 Bf[24];
        #pragma unroll
        for (int i = 0; i < 24; ++i) Bf[i] = *(const bf16x8*)(wrow + i * 32 + kb2 * 8);

        const int g_row = tid >> 5, g_col = tid & 31;
        float bias_r = 0.f, bias_z = 0.f, bias_xn = 0.f, bias_hn = 0.f;
        if (tid < 256) {
            const int j = j0 + g_col;
            bias_r  = b_ih[j] + b_hh[j];
            bias_z  = b_ih[512 + j] + b_hh[512 + j];
            bias_xn = b_ih[1024 + j];
            bias_hn = b_hh[1024 + j];
        }
        float hold1 = 0.f, hold2 = 0.f;

        // prefetch phi t=0
        #pragma unroll
        for (int it = 0; it < 3; ++it) {
            const int c = tid + it * 384;
            if (c < 1024) {
                const int m = c >> 6, q = c & 63;
                *(unsigned long long*)(phi_s0 + m * PHI_PITCH + q * 4) =
                    *(const unsigned long long*)(phi + ((size_t)(b0 + m)) * E_SZ + q * 4);
            }
        }

        for (int t = 0; t < T_LEN - 1; ++t) {
            const int buf = t & 1;
            const short* phi_cur = buf ? phi_s1 : phi_s0;
            const unsigned tg = (unsigned)t & 0xFFFFu;

            // staging + implicit barrier: poll tagged h words
            const unsigned long long* hx64 =
                (const unsigned long long*)hx + ((size_t)(buf * 8 + bt)) * 4096;
            unsigned long long v[11];
            #pragma unroll
            for (int it = 0; it < 11; ++it) {
                const int c = tid + it * 384;
                if (c < 4096) v[it] = llc_load_u64(hx64 + c);
            }
            while (true) {
                unsigned bad = 0;
                #pragma unroll
                for (int it = 0; it < 11; ++it) {
                    const int c = tid + it * 384;
                    if (c < 4096) {
                        const unsigned t0 = (unsigned)v[it] & 0xFFFFu;
                        const unsigned t1 = (unsigned)(v[it] >> 32) & 0xFFFFu;
                        if ((t0 ^ tg) | (t1 ^ tg)) bad |= (1u << it);
                    }
                }
                if (bad == 0) break;
                #pragma unroll
                for (int it = 0; it < 11; ++it)
                    if (bad & (1u << it)) v[it] = llc_load_u64(hx64 + tid + it * 384);
            }
            #pragma unroll
            for (int it = 0; it < 11; ++it) {
                const int c = tid + it * 384;
                if (c < 4096) {
                    const int ctp = c >> 8, w = c & 255, row = w >> 4, colp = w & 15;
                    const unsigned lo = (unsigned)(v[it] >> 16) & 0xFFFFu;
                    const unsigned hi = (unsigned)(v[it] >> 48) & 0xFFFFu;
                    *(unsigned*)(act_s + row * ACT_PITCH + ctp * 32 + colp * 2) = lo | (hi << 16);
                }
            }
            __syncthreads();
            // publish: hs rows <= t are at LLC (drained by the sync above)
            if (tid == 0 && t)
                __hip_atomic_store(cnt + blockIdx.x, (unsigned)t,
                                   __ATOMIC_RELAXED, __HIP_MEMORY_SCOPE_AGENT);

            // next phi prefetch (held in regs)
            unsigned long long pv[3];
            const int tn = t + 1;
            if (tn < T_LEN - 1) {
                #pragma unroll
                for (int it = 0; it < 3; ++it) {
                    const int c = tid + it * 384;
                    if (c < 1024) {
                        const int m = c >> 6, q = c & 63;
                        pv[it] = *(const unsigned long long*)(
                            phi + ((size_t)tn * B_SZ + b0 + m) * E_SZ + q * 4);
                    }
                }
            }

            // MFMA: split accumulate chains (even/odd k-blocks)
            {
                const short* arow = act_s + a_row * ACT_PITCH;
                const short* prow = phi_cur + a_row * PHI_PITCH;
                f32x4 acc0 = {0.f, 0.f, 0.f, 0.f};
                f32x4 acc1 = {0.f, 0.f, 0.f, 0.f};
                #pragma unroll
                for (int i = 0; i < 16; i += 2) {
                    bf16x8 a0 = *(const bf16x8*)(arow + i * 32 + kb2 * 8);
                    bf16x8 a1 = *(const bf16x8*)(arow + (i + 1) * 32 + kb2 * 8);
                    acc0 = __builtin_amdgcn_mfma_f32_16x16x32_bf16(a0, Bf[i], acc0, 0, 0, 0);
                    acc1 = __builtin_amdgcn_mfma_f32_16x16x32_bf16(a1, Bf[i + 1], acc1, 0, 0, 0);
                }
                if (gt < 2) {
                    #pragma unroll
                    for (int i = 16; i < 24; i += 2) {
                        bf16x8 a0 = *(const bf16x8*)(prow + (i - 16) * 32 + kb2 * 8);
                        bf16x8 a1 = *(const bf16x8*)(prow + (i - 15) * 32 + kb2 * 8);
                        acc0 = __builtin_amdgcn_mfma_f32_16x16x32_bf16(a0, Bf[i], acc0, 0, 0, 0);
                        acc1 = __builtin_amdgcn_mfma_f32_16x16x32_bf16(a1, Bf[i + 1], acc1, 0, 0, 0);
                    }
                    #pragma unroll
                    for (int i2 = 0; i2 < 4; ++i2)
                        g_s[gt * 16 * GP + ((L >> 4) * 4 + i2) * GP + ch * 16 + n_loc] =
                            acc0[i2] + acc1[i2];
                } else {
                    f32x4 accB = {0.f, 0.f, 0.f, 0.f};
                    #pragma unroll
                    for (int i = 16; i < 24; ++i) {
                        bf16x8 a = *(const bf16x8*)(prow + (i - 16) * 32 + kb2 * 8);
                        accB = __builtin_amdgcn_mfma_f32_16x16x32_bf16(a, Bf[i], accB, 0, 0, 0);
                    }
                    #pragma unroll
                    for (int i2 = 0; i2 < 4; ++i2) {
                        const int idx = ((L >> 4) * 4 + i2) * GP + ch * 16 + n_loc;
                        g_s[2 * 16 * GP + idx] = acc0[i2] + acc1[i2];   // hn
                        g_s[3 * 16 * GP + idx] = accB[i2];              // xn
                    }
                }
            }

            // commit prefetched phi
            if (tn < T_LEN - 1) {
                short* pbuf = (tn & 1) ? phi_s1 : phi_s0;
                #pragma unroll
                for (int it = 0; it < 3; ++it) {
                    const int c = tid + it * 384;
                    if (c < 1024) {
                        const int m = c >> 6, q = c & 63;
                        *(unsigned long long*)(pbuf + m * PHI_PITCH + q * 4) = pv[it];
                    }
                }
            }
            __syncthreads();

            // gate math + state update + tagged store
            if (tid < 256) {
                const int nb = (t + 1) & 1;
                unsigned* hxdst = hx + ((size_t)(nb * 8 + bt) * 16 + ct) * 512;
                #pragma unroll
                for (int half = 0; half < 2; ++half) {
                    const int row = g_row + half * 8;
                    const int idx = row * GP + g_col;
                    float& hold = half ? hold2 : hold1;
                    const float pre_r = g_s[0 * 16 * GP + idx] + bias_r;
                    const float pre_z = g_s[1 * 16 * GP + idx] + bias_z;
                    const float hn    = g_s[2 * 16 * GP + idx] + bias_hn;
                    const float xn    = g_s[3 * 16 * GP + idx] + bias_xn;
                    const float r = 1.f / (1.f + __expf(-pre_r));
                    const float z = 1.f / (1.f + __expf(-pre_z));
                    const float e2 = __expf(-2.f * fmaf(r, hn, xn));
                    const float n = (1.f - e2) / (1.f + e2);          // tanh
                    const float hnew = fmaf(z, hold - n, n);          // (1-z)*n + z*h
                    hold = hnew;
                    __hip_atomic_store(
                        hs + (size_t)(t + 1) * B_SZ * H_SZ + (size_t)(b0 + row) * H_SZ + j0 + g_col,
                        hnew, __ATOMIC_RELAXED, __HIP_MEMORY_SCOPE_AGENT);
                    if (t < T_LEN - 2)
                        __hip_atomic_store(hxdst + row * 32 + g_col,
                                           ((unsigned)f2bf(hnew) << 16) | ((unsigned)(t + 1) & 0xFFFFu),
                                           __ATOMIC_RELAXED, __HIP_MEMORY_SCOPE_AGENT);
                }
            }
        }
        __syncthreads();   // drain final hs stores
        if (tid == 0)
            __hip_atomic_store(cnt + blockIdx.x, (unsigned)(T_LEN - 1),
                               __ATOMIC_RELAXED, __HIP_MEMORY_SCOPE_AGENT);
    } else {
        // ================= LOSS PATH =================
        float* hsT  = (float*)(smem + L_HST);            // [16][HS_PITCH]
        float* he_s = (float*)(smem + L_HES);            // [16][129]
        unsigned short* wmu_s = (unsigned short*)(smem + L_WMU);  // [31][WM_PITCH] bf16
        unsigned short* wlv_s = (unsigned short*)(smem + L_WLV);
        float* hinf_s = (float*)(smem + L_HINF);         // [128]
        float* red    = (float*)(smem + L_HINF) + 128;   // [6]

        const int i = blockIdx.x - 128;
        const int lb = i & 7, ls = i >> 3;
        const int b0 = lb * 16;

        for (int k = tid; k < MD * S_SZ; k += 384) {
            wmu_s[(k >> 7) * WM_PITCH + (k & 127)] = f2bf(W_mu[k]);
            wlv_s[(k >> 7) * WM_PITCH + (k & 127)] = f2bf(W_lv[k]);
        }
        if (tid < S_SZ) hinf_s[tid] = h_inf[tid];
        __syncthreads();

        float lacc = 0.f;
        for (int s = 0; s < 32; ++s) {
            const int t = 1 + ls + 16 * s;
            if (t > T_LEN - 1) break;
            // wait for all 16 ct producer blocks of group lb to pass step t
            if (tid < 64) {
                while (true) {
                    unsigned cv = 0xFFFFFFFFu;
                    if (tid < 16) cv = llc_load_u32(cnt + lb + 8 * tid);
                    if (__ballot(cv >= (unsigned)t) == ~0ull) break;
                    __builtin_amdgcn_s_sleep(16);
                }
            }
            __syncthreads();
            // stage hs tile (16 rows x 512 fp32) via LLC-coherent u64 loads
            const unsigned long long* hs64 =
                (const unsigned long long*)(hs + ((size_t)t * B_SZ + b0) * H_SZ);
            #pragma unroll
            for (int it = 0; it < 11; ++it) {
                const int c = tid + it * 384;
                if (c < 4096) {
                    const int m = c >> 8, q = c & 255;   // row, u64-in-row
                    unsigned long long v = llc_load_u64(hs64 + (size_t)m * 256 + q);
                    *(unsigned long long*)(hsT + m * HS_PITCH + q * 2) = v;
                }
            }
            __syncthreads();
            // phase 1: he = relu(W_he . h + b_he)
            if (tid < 256) {
                const int c = tid & 127, rg = tid >> 7;
                const float* __restrict__ wr = W_he + (size_t)c * H_SZ;
                float acc[8];
                #pragma unroll
                for (int ii = 0; ii < 8; ++ii) acc[ii] = b_he[c];
                for (int k = 0; k < H_SZ; k += 4) {
                    const float4 w4 = *(const float4*)(wr + k);
                    #pragma unroll
                    for (int ii = 0; ii < 8; ++ii) {
                        const float4 h4 = *(const float4*)(hsT + (rg * 8 + ii) * HS_PITCH + k);
                        acc[ii] = fmaf(w4.x, h4.x, acc[ii]);
                        acc[ii] = fmaf(w4.y, h4.y, acc[ii]);
                        acc[ii] = fmaf(w4.z, h4.z, acc[ii]);
                        acc[ii] = fmaf(w4.w, h4.w, acc[ii]);
                    }
                }
                #pragma unroll
                for (int ii = 0; ii < 8; ++ii)
                    he_s[(rg * 8 + ii) * 129 + c] = fmaxf(acc[ii], 0.f);
            }
            __syncthreads();
            // phase 2: markers + time LL
            if (tid < 256) {
                const int r = tid >> 4, q = tid & 15;
                const int row = t * B_SZ + b0 + r;
                const float mk = mask[row];
                #pragma unroll
                for (int pass = 0; pass < 2; ++pass) {
                    const int m = q + pass * 16;
                    if (m < MD) {
                        float mu = b_mu[m], lv = b_lv[m];
                        for (int c2 = 0; c2 < S_SZ; ++c2) {
                            const float h = he_s[r * 129 + c2];
                            mu = fmaf(h, bf2f(wmu_s[m * WM_PITCH + c2]), mu);
                            lv = fmaf(h, bf2f(wlv_s[m * WM_PITCH + c2]), lv);
                        }
                        const float lsg   = fmaxf(0.5f * lv, LOG001);
                        const float inv_s = __expf(-lsg);
                        const float zz    = (x[(size_t)row * MD + m] - mu) * inv_s;
                        lacc += (0.5f * zz * zz + lsg + HALF_L2PI) * mk;
                    }
                }
                if (q == 0) {
                    float past = 0.f;
                    for (int c2 = 0; c2 < S_SZ; ++c2)
                        past = fmaf(he_s[r * 129 + c2], hinf_s[c2], past);
                    const float ti = time_inf[0], bi = base_int[0];
                    const float dt = t_in[(size_t)row * 2 + 1];
                    const float term1 = past + ti * dt + bi;
                    const float tll = term1 + (__expf(past + bi) - __expf(term1)) / ti;
                    lacc += GAMMA_F * (-tll) * mk;
                }
            }
            __syncthreads();   // he_s/hsT reuse safety for next tile
        }
        // block reduce -> one atomic
        #pragma unroll
        for (int off = 32; off > 0; off >>= 1) lacc += __shfl_down(lacc, off, 64);
        if ((tid & 63) == 0) red[tid >> 6] = lacc;
        __syncthreads();
        if (tid == 0) {
            float sum = 0.f;
            #pragma unroll
            for (int w = 0; w < 6; ++w) sum += red[w];
            atomicAdd(out, sum);
        }
    }
}

extern "C" void kernel_launch(void* const* d_in, const int* in_sizes, int n_in,
                              void* d_out, int out_size, void* d_ws, size_t ws_size,
                              hipStream_t stream) {
    const float* x       = (const float*)d_in[0];
    const float* t_in    = (const float*)d_in[1];
    const float* mask    = (const float*)d_in[2];
    const float* W_embed = (const float*)d_in[3];
    const float* b_embed = (const float*)d_in[4];
    const float* W_ih    = (const float*)d_in[5];
    const float* b_ih    = (const float*)d_in[6];
    const float* W_hh    = (const float*)d_in[7];
    const float* b_hh    = (const float*)d_in[8];
    const float* W_he    = (const float*)d_in[9];
    const float* b_he    = (const float*)d_in[10];
    const float* W_mu    = (const float*)d_in[11];
    const float* b_mu    = (const float*)d_in[12];
    const float* W_lv    = (const float*)d_in[13];
    const float* b_lv    = (const float*)d_in[14];
    const float* h_inf   = (const float*)d_in[15];
    const float* tinf    = (const float*)d_in[16];
    const float* bint    = (const float*)d_in[17];
    float* out = (float*)d_out;

    // ws layout (bytes), 256-aligned:
    // phi_bf16 33.5M | hs fp32 134.2M | wpack_bf16 2.36M | hx 512K | cnt 512B
    char* ws = (char*)d_ws;
    const size_t OFF_PHI = 0;
    const size_t OFF_HS  = 33554432ull;
    const size_t OFF_WP  = 167772160ull;
    const size_t OFF_HX  = 170131456ull;
    const size_t OFF_CNT = 170655744ull;
    const size_t TOTAL   = 170656256ull;
    if (ws_size < TOTAL) return;
    unsigned short* phi   = (unsigned short*)(ws + OFF_PHI);
    float*          hsbuf = (float*)(ws + OFF_HS);
    unsigned short* wpack = (unsigned short*)(ws + OFF_WP);
    unsigned*       hx    = (unsigned*)(ws + OFF_HX);
    unsigned*       cnt   = (unsigned*)(ws + OFF_CNT);

    zero_init<<<dim3(256), 256, 0, stream>>>(hx, cnt, out);
    pack_w<<<dim3(512), 256, 0, stream>>>(W_ih, W_hh, wpack);
    embed_phi<<<dim3(1024), 256, 0, stream>>>(x, W_embed, b_embed, phi);

    void* args[] = {(void*)&wpack, (void*)&phi, (void*)&hx, (void*)&hsbuf,
                    (void*)&b_ih, (void*)&b_hh, (void*)&cnt,
                    (void*)&W_he, (void*)&b_he, (void*)&W_mu, (void*)&b_mu,
                    (void*)&W_lv, (void*)&b_lv, (void*)&h_inf, (void*)&tinf,
                    (void*)&bint, (void*)&x, (void*)&t_in, (void*)&mask, (void*)&out};
    hipLaunchCooperativeKernel((void*)fused_persist, dim3(256), dim3(384), args, 0, stream);
}

// Round 8
// 1720.375 us; speedup vs baseline: 28.5697x; 1.2242x over previous
//
#include <hip/hip_runtime.h>
#include <cstddef>
#include <cstdint>

// Model dims (fixed by reference)
#define T_LEN 512
#define B_SZ  128
#define MD    31
#define E_SZ  256
#define H_SZ  512
#define S_SZ  128
#define GAMMA_F 1.0f
#define LOG001   -4.605170185988091f   // log(0.01)
#define HALF_L2PI 0.9189385332046727f  // 0.5*log(2*pi)

typedef __attribute__((ext_vector_type(8))) short bf16x8;   // 8 bf16 in 4 VGPRs
typedef __attribute__((ext_vector_type(4))) float f32x4;

#define ACT_PITCH 536   // shorts: 512 + 24 pad
#define PHI_PITCH 264   // shorts: 256 + 8 pad
#define GP        36    // gate-array col pitch (floats)
#define HS_PITCH  516   // loss hs tile pitch (floats)
#define WM_PITCH  132   // loss wmu/wlv pitch (ushorts)
#define CNT_STRIDE 16   // dwords: one 64B line per counter (de-hotspot)

// ---- shared-memory union (max of recurrence 43.3KB / loss 58.2KB) ----
#define SMEM_BYTES 58240
// recurrence offsets
#define R_ACT  0
#define R_PHI  17152
#define R_GS   34048
// loss offsets
#define L_HST  0
#define L_HES  33024
#define L_WMU  41280
#define L_WLV  49464
#define L_HINF 57648

__device__ inline unsigned short f2bf(float f) {   // fp32 -> bf16 bits, RNE
    union { float f; unsigned u; } v; v.f = f;
    unsigned r = v.u + 0x7FFFu + ((v.u >> 16) & 1u);
    return (unsigned short)(r >> 16);
}
__device__ inline float bf2f(unsigned short u) {
    union { unsigned u; float f; } v; v.u = (unsigned)u << 16; return v.f;
}
__device__ inline unsigned long long llc_load_u64(const unsigned long long* p) {
    return __hip_atomic_load(p, __ATOMIC_RELAXED, __HIP_MEMORY_SCOPE_AGENT);
}
__device__ inline unsigned llc_load_u32(const unsigned* p) {
    return __hip_atomic_load(p, __ATOMIC_RELAXED, __HIP_MEMORY_SCOPE_AGENT);
}

// ---------------- zero/init: hx buf0 = 0 (tag0 + h=0), counters = 0, out = 0 -----------------
__global__ void zero_init(unsigned* __restrict__ hx, unsigned* __restrict__ cnt,
                          float* __restrict__ out) {
    int i = blockIdx.x * blockDim.x + threadIdx.x;
    if (i < 65536) hx[i] = 0u;   // buf0: 8 bt x 16 ct x 512 u32
    if (i < 128 * CNT_STRIDE) cnt[i] = 0u;
    if (i == 0) out[0] = 0.f;
}

// ---------------- pack W -> bf16: wpack[col][768] = [W_hh[col][0:512] | W_ih[col][0:256]] ----
__global__ void pack_w(const float* __restrict__ W_ih, const float* __restrict__ W_hh,
                       unsigned short* __restrict__ wpack) {
    const int n = 1536 * 768;
    for (int i = blockIdx.x * blockDim.x + threadIdx.x; i < n; i += gridDim.x * blockDim.x) {
        int col = i / 768, k = i - col * 768;
        float v = (k < H_SZ) ? W_hh[col * H_SZ + k] : W_ih[col * E_SZ + (k - H_SZ)];
        wpack[i] = f2bf(v);
    }
}

// ---------------- embed: phi_bf16[row][e] = bf16(relu(b_embed[e] + x[row]·W_embed[e])) -------
__global__ __launch_bounds__(256) void embed_phi(
    const float* __restrict__ x, const float* __restrict__ W_embed,
    const float* __restrict__ b_embed, unsigned short* __restrict__ phi) {
    __shared__ float xs[8][32];
    const int e = threadIdx.x;
    float w[MD];
    #pragma unroll
    for (int m = 0; m < MD; ++m) w[m] = W_embed[e * MD + m];
    const float be = b_embed[e];
    const int nblocks = (T_LEN * B_SZ) / 8;
    for (int rb = blockIdx.x; rb < nblocks; rb += gridDim.x) {
        const int r0 = rb * 8;
        if (threadIdx.x < 8 * MD)
            xs[threadIdx.x / MD][threadIdx.x % MD] = x[(size_t)r0 * MD + threadIdx.x];
        __syncthreads();
        #pragma unroll
        for (int i = 0; i < 8; ++i) {
            float acc = be;
            #pragma unroll
            for (int m = 0; m < MD; ++m) acc = fmaf(xs[i][m], w[m], acc);
            phi[(size_t)(r0 + i) * E_SZ + e] = f2bf(fmaxf(acc, 0.f));
        }
        __syncthreads();
    }
}

// ---------------- fused persistent kernel: 128 recurrence blocks + 128 loss blocks ----------
__global__ __launch_bounds__(384) void fused_persist(
    const unsigned short* __restrict__ wpack, const unsigned short* __restrict__ phi,
    unsigned* __restrict__ hx, float* __restrict__ hs,
    const float* __restrict__ b_ih, const float* __restrict__ b_hh,
    unsigned* __restrict__ cnt,
    const float* __restrict__ W_he, const float* __restrict__ b_he,
    const float* __restrict__ W_mu, const float* __restrict__ b_mu,
    const float* __restrict__ W_lv, const float* __restrict__ b_lv,
    const float* __restrict__ h_inf, const float* __restrict__ time_inf,
    const float* __restrict__ base_int, const float* __restrict__ x,
    const float* __restrict__ t_in, const float* __restrict__ mask,
    float* __restrict__ out) {
    __shared__ __align__(16) char smem[SMEM_BYTES];
    const int tid = threadIdx.x;

    if (blockIdx.x < 128) {
        // ================= RECURRENCE PATH =================
        short* act_s = (short*)(smem + R_ACT);
        short* phi_s0 = (short*)(smem + R_PHI);
        short* phi_s1 = (short*)(smem + R_PHI) + 16 * PHI_PITCH;
        float* g_s = (float*)(smem + R_GS);     // [4][16*GP]

        const int bt = blockIdx.x & 7, ct = blockIdx.x >> 3;
        const int b0 = bt * 16, j0 = ct * 32;
        const int wid = tid >> 6, L = tid & 63;
        const int gt = wid >> 1, ch = wid & 1;
        const int n_loc = L & 15, kb2 = L >> 4;
        const int a_row = L & 15;

        const unsigned short* __restrict__ wrow =
            wpack + (size_t)(gt * 512 + j0 + ch * 16 + n_loc) * 768;
        bf16x8 Bf[24];
        #pragma unroll
        for (int i = 0; i < 24; ++i) Bf[i] = *(const bf16x8*)(wrow + i * 32 + kb2 * 8);

        const int g_row = tid >> 5, g_col = tid & 31;
        float bias_r = 0.f, bias_z = 0.f, bias_xn = 0.f, bias_hn = 0.f;
        if (tid < 256) {
            const int j = j0 + g_col;
            bias_r  = b_ih[j] + b_hh[j];
            bias_z  = b_ih[512 + j] + b_hh[512 + j];
            bias_xn = b_ih[1024 + j];
            bias_hn = b_hh[1024 + j];
        }
        float hold1 = 0.f, hold2 = 0.f;

        // prefetch phi t=0
        #pragma unroll
        for (int it = 0; it < 3; ++it) {
            const int c = tid + it * 384;
            if (c < 1024) {
                const int m = c >> 6, q = c & 63;
                *(unsigned long long*)(phi_s0 + m * PHI_PITCH + q * 4) =
                    *(const unsigned long long*)(phi + ((size_t)(b0 + m)) * E_SZ + q * 4);
            }
        }

        for (int t = 0; t < T_LEN - 1; ++t) {
            const int buf = t & 1;
            const short* phi_cur = buf ? phi_s1 : phi_s0;
            const unsigned tg = (unsigned)t & 0xFFFFu;

            // staging + implicit barrier: poll tagged h words (throttled retries)
            const unsigned long long* hx64 =
                (const unsigned long long*)hx + ((size_t)(buf * 8 + bt)) * 4096;
            unsigned long long v[11];
            #pragma unroll
            for (int it = 0; it < 11; ++it) {
                const int c = tid + it * 384;
                if (c < 4096) v[it] = llc_load_u64(hx64 + c);
            }
            while (true) {
                unsigned bad = 0;
                #pragma unroll
                for (int it = 0; it < 11; ++it) {
                    const int c = tid + it * 384;
                    if (c < 4096) {
                        const unsigned t0 = (unsigned)v[it] & 0xFFFFu;
                        const unsigned t1 = (unsigned)(v[it] >> 32) & 0xFFFFu;
                        if ((t0 ^ tg) | (t1 ^ tg)) bad |= (1u << it);
                    }
                }
                if (bad == 0) break;
                __builtin_amdgcn_s_sleep(1);   // throttle spin traffic at the LLC
                #pragma unroll
                for (int it = 0; it < 11; ++it)
                    if (bad & (1u << it)) v[it] = llc_load_u64(hx64 + tid + it * 384);
            }
            #pragma unroll
            for (int it = 0; it < 11; ++it) {
                const int c = tid + it * 384;
                if (c < 4096) {
                    const int ctp = c >> 8, w = c & 255, row = w >> 4, colp = w & 15;
                    const unsigned lo = (unsigned)(v[it] >> 16) & 0xFFFFu;
                    const unsigned hi = (unsigned)(v[it] >> 48) & 0xFFFFu;
                    *(unsigned*)(act_s + row * ACT_PITCH + ctp * 32 + colp * 2) = lo | (hi << 16);
                }
            }
            __syncthreads();
            // publish: hs rows <= t are at LLC (drained by the sync above)
            if (tid == 0 && t)
                __hip_atomic_store(cnt + blockIdx.x * CNT_STRIDE, (unsigned)t,
                                   __ATOMIC_RELAXED, __HIP_MEMORY_SCOPE_AGENT);

            // next phi prefetch (held in regs)
            unsigned long long pv[3];
            const int tn = t + 1;
            if (tn < T_LEN - 1) {
                #pragma unroll
                for (int it = 0; it < 3; ++it) {
                    const int c = tid + it * 384;
                    if (c < 1024) {
                        const int m = c >> 6, q = c & 63;
                        pv[it] = *(const unsigned long long*)(
                            phi + ((size_t)tn * B_SZ + b0 + m) * E_SZ + q * 4);
                    }
                }
            }

            // MFMA: split accumulate chains (even/odd k-blocks)
            {
                const short* arow = act_s + a_row * ACT_PITCH;
                const short* prow = phi_cur + a_row * PHI_PITCH;
                f32x4 acc0 = {0.f, 0.f, 0.f, 0.f};
                f32x4 acc1 = {0.f, 0.f, 0.f, 0.f};
                #pragma unroll
                for (int i = 0; i < 16; i += 2) {
                    bf16x8 a0 = *(const bf16x8*)(arow + i * 32 + kb2 * 8);
                    bf16x8 a1 = *(const bf16x8*)(arow + (i + 1) * 32 + kb2 * 8);
                    acc0 = __builtin_amdgcn_mfma_f32_16x16x32_bf16(a0, Bf[i], acc0, 0, 0, 0);
                    acc1 = __builtin_amdgcn_mfma_f32_16x16x32_bf16(a1, Bf[i + 1], acc1, 0, 0, 0);
                }
                if (gt < 2) {
                    #pragma unroll
                    for (int i = 16; i < 24; i += 2) {
                        bf16x8 a0 = *(const bf16x8*)(prow + (i - 16) * 32 + kb2 * 8);
                        bf16x8 a1 = *(const bf16x8*)(prow + (i - 15) * 32 + kb2 * 8);
                        acc0 = __builtin_amdgcn_mfma_f32_16x16x32_bf16(a0, Bf[i], acc0, 0, 0, 0);
                        acc1 = __builtin_amdgcn_mfma_f32_16x16x32_bf16(a1, Bf[i + 1], acc1, 0, 0, 0);
                    }
                    #pragma unroll
                    for (int i2 = 0; i2 < 4; ++i2)
                        g_s[gt * 16 * GP + ((L >> 4) * 4 + i2) * GP + ch * 16 + n_loc] =
                            acc0[i2] + acc1[i2];
                } else {
                    f32x4 accB = {0.f, 0.f, 0.f, 0.f};
                    #pragma unroll
                    for (int i = 16; i < 24; ++i) {
                        bf16x8 a = *(const bf16x8*)(prow + (i - 16) * 32 + kb2 * 8);
                        accB = __builtin_amdgcn_mfma_f32_16x16x32_bf16(a, Bf[i], accB, 0, 0, 0);
                    }
                    #pragma unroll
                    for (int i2 = 0; i2 < 4; ++i2) {
                        const int idx = ((L >> 4) * 4 + i2) * GP + ch * 16 + n_loc;
                        g_s[2 * 16 * GP + idx] = acc0[i2] + acc1[i2];   // hn
                        g_s[3 * 16 * GP + idx] = accB[i2];              // xn
                    }
                }
            }

            // commit prefetched phi
            if (tn < T_LEN - 1) {
                short* pbuf = (tn & 1) ? phi_s1 : phi_s0;
                #pragma unroll
                for (int it = 0; it < 3; ++it) {
                    const int c = tid + it * 384;
                    if (c < 1024) {
                        const int m = c >> 6, q = c & 63;
                        *(unsigned long long*)(pbuf + m * PHI_PITCH + q * 4) = pv[it];
                    }
                }
            }
            __syncthreads();

            // gate math + state update + tagged store
            if (tid < 256) {
                const int nb = (t + 1) & 1;
                unsigned* hxdst = hx + ((size_t)(nb * 8 + bt) * 16 + ct) * 512;
                #pragma unroll
                for (int half = 0; half < 2; ++half) {
                    const int row = g_row + half * 8;
                    const int idx = row * GP + g_col;
                    float& hold = half ? hold2 : hold1;
                    const float pre_r = g_s[0 * 16 * GP + idx] + bias_r;
                    const float pre_z = g_s[1 * 16 * GP + idx] + bias_z;
                    const float hn    = g_s[2 * 16 * GP + idx] + bias_hn;
                    const float xn    = g_s[3 * 16 * GP + idx] + bias_xn;
                    const float r = 1.f / (1.f + __expf(-pre_r));
                    const float z = 1.f / (1.f + __expf(-pre_z));
                    const float e2 = __expf(-2.f * fmaf(r, hn, xn));
                    const float n = (1.f - e2) / (1.f + e2);          // tanh
                    const float hnew = fmaf(z, hold - n, n);          // (1-z)*n + z*h
                    hold = hnew;
                    __hip_atomic_store(
                        hs + (size_t)(t + 1) * B_SZ * H_SZ + (size_t)(b0 + row) * H_SZ + j0 + g_col,
                        hnew, __ATOMIC_RELAXED, __HIP_MEMORY_SCOPE_AGENT);
                    if (t < T_LEN - 2)
                        __hip_atomic_store(hxdst + row * 32 + g_col,
                                           ((unsigned)f2bf(hnew) << 16) | ((unsigned)(t + 1) & 0xFFFFu),
                                           __ATOMIC_RELAXED, __HIP_MEMORY_SCOPE_AGENT);
                }
            }
        }
        __syncthreads();   // drain final hs stores
        if (tid == 0)
            __hip_atomic_store(cnt + blockIdx.x * CNT_STRIDE, (unsigned)(T_LEN - 1),
                               __ATOMIC_RELAXED, __HIP_MEMORY_SCOPE_AGENT);
    } else {
        // ================= LOSS PATH =================
        float* hsT  = (float*)(smem + L_HST);            // [16][HS_PITCH]
        float* he_s = (float*)(smem + L_HES);            // [16][129]
        unsigned short* wmu_s = (unsigned short*)(smem + L_WMU);  // [31][WM_PITCH] bf16
        unsigned short* wlv_s = (unsigned short*)(smem + L_WLV);
        float* hinf_s = (float*)(smem + L_HINF);         // [128]
        float* red    = (float*)(smem + L_HINF) + 128;   // [6]

        const int i = blockIdx.x - 128;
        const int lb = i & 7, ls = i >> 3;
        const int b0 = lb * 16;

        for (int k = tid; k < MD * S_SZ; k += 384) {
            wmu_s[(k >> 7) * WM_PITCH + (k & 127)] = f2bf(W_mu[k]);
            wlv_s[(k >> 7) * WM_PITCH + (k & 127)] = f2bf(W_lv[k]);
        }
        if (tid < S_SZ) hinf_s[tid] = h_inf[tid];
        __syncthreads();

        float lacc = 0.f;
        for (int s = 0; s < 32; ++s) {
            const int t = 1 + ls + 16 * s;
            if (t > T_LEN - 1) break;
            // wait for all 16 ct producer blocks of group lb to pass step t
            // (each counter is one 64B line; 16 pollers/line; slow cadence)
            if (tid < 64) {
                while (true) {
                    unsigned cv = 0xFFFFFFFFu;
                    if (tid < 16) cv = llc_load_u32(cnt + (lb + 8 * tid) * CNT_STRIDE);
                    if (__ballot(cv >= (unsigned)t) == ~0ull) break;
                    __builtin_amdgcn_s_sleep(64);
                }
            }
            __syncthreads();
            // stage hs tile (16 rows x 512 fp32) via LLC-coherent u64 loads
            const unsigned long long* hs64 =
                (const unsigned long long*)(hs + ((size_t)t * B_SZ + b0) * H_SZ);
            #pragma unroll
            for (int it = 0; it < 11; ++it) {
                const int c = tid + it * 384;
                if (c < 4096) {
                    const int m = c >> 8, q = c & 255;   // row, u64-in-row
                    unsigned long long v = llc_load_u64(hs64 + (size_t)m * 256 + q);
                    *(unsigned long long*)(hsT + m * HS_PITCH + q * 2) = v;
                }
            }
            __syncthreads();
            // phase 1: he = relu(W_he . h + b_he)
            if (tid < 256) {
                const int c = tid & 127, rg = tid >> 7;
                const float* __restrict__ wr = W_he + (size_t)c * H_SZ;
                float acc[8];
                #pragma unroll
                for (int ii = 0; ii < 8; ++ii) acc[ii] = b_he[c];
                for (int k = 0; k < H_SZ; k += 4) {
                    const float4 w4 = *(const float4*)(wr + k);
                    #pragma unroll
                    for (int ii = 0; ii < 8; ++ii) {
                        const float4 h4 = *(const float4*)(hsT + (rg * 8 + ii) * HS_PITCH + k);
                        acc[ii] = fmaf(w4.x, h4.x, acc[ii]);
                        acc[ii] = fmaf(w4.y, h4.y, acc[ii]);
                        acc[ii] = fmaf(w4.z, h4.z, acc[ii]);
                        acc[ii] = fmaf(w4.w, h4.w, acc[ii]);
                    }
                }
                #pragma unroll
                for (int ii = 0; ii < 8; ++ii)
                    he_s[(rg * 8 + ii) * 129 + c] = fmaxf(acc[ii], 0.f);
            }
            __syncthreads();
            // phase 2: markers + time LL
            if (tid < 256) {
                const int r = tid >> 4, q = tid & 15;
                const int row = t * B_SZ + b0 + r;
                const float mk = mask[row];
                #pragma unroll
                for (int pass = 0; pass < 2; ++pass) {
                    const int m = q + pass * 16;
                    if (m < MD) {
                        float mu = b_mu[m], lv = b_lv[m];
                        for (int c2 = 0; c2 < S_SZ; ++c2) {
                            const float h = he_s[r * 129 + c2];
                            mu = fmaf(h, bf2f(wmu_s[m * WM_PITCH + c2]), mu);
                            lv = fmaf(h, bf2f(wlv_s[m * WM_PITCH + c2]), lv);
                        }
                        const float lsg   = fmaxf(0.5f * lv, LOG001);
                        const float inv_s = __expf(-lsg);
                        const float zz    = (x[(size_t)row * MD + m] - mu) * inv_s;
                        lacc += (0.5f * zz * zz + lsg + HALF_L2PI) * mk;
                    }
                }
                if (q == 0) {
                    float past = 0.f;
                    for (int c2 = 0; c2 < S_SZ; ++c2)
                        past = fmaf(he_s[r * 129 + c2], hinf_s[c2], past);
                    const float ti = time_inf[0], bi = base_int[0];
                    const float dt = t_in[(size_t)row * 2 + 1];
                    const float term1 = past + ti * dt + bi;
                    const float tll = term1 + (__expf(past + bi) - __expf(term1)) / ti;
                    lacc += GAMMA_F * (-tll) * mk;
                }
            }
            __syncthreads();   // he_s/hsT reuse safety for next tile
        }
        // block reduce -> one atomic
        #pragma unroll
        for (int off = 32; off > 0; off >>= 1) lacc += __shfl_down(lacc, off, 64);
        if ((tid & 63) == 0) red[tid >> 6] = lacc;
        __syncthreads();
        if (tid == 0) {
            float sum = 0.f;
            #pragma unroll
            for (int w = 0; w < 6; ++w) sum += red[w];
            atomicAdd(out, sum);
        }
    }
}

extern "C" void kernel_launch(void* const* d_in, const int* in_sizes, int n_in,
                              void* d_out, int out_size, void* d_ws, size_t ws_size,
                              hipStream_t stream) {
    const float* x       = (const float*)d_in[0];
    const float* t_in    = (const float*)d_in[1];
    const float* mask    = (const float*)d_in[2];
    const float* W_embed = (const float*)d_in[3];
    const float* b_embed = (const float*)d_in[4];
    const float* W_ih    = (const float*)d_in[5];
    const float* b_ih    = (const float*)d_in[6];
    const float* W_hh    = (const float*)d_in[7];
    const float* b_hh    = (const float*)d_in[8];
    const float* W_he    = (const float*)d_in[9];
    const float* b_he    = (const float*)d_in[10];
    const float* W_mu    = (const float*)d_in[11];
    const float* b_mu    = (const float*)d_in[12];
    const float* W_lv    = (const float*)d_in[13];
    const float* b_lv    = (const float*)d_in[14];
    const float* h_inf   = (const float*)d_in[15];
    const float* tinf    = (const float*)d_in[16];
    const float* bint    = (const float*)d_in[17];
    float* out = (float*)d_out;

    // ws layout (bytes), 256-aligned:
    // phi_bf16 33.5M | hs fp32 134.2M | wpack_bf16 2.36M | hx 512K | cnt 8K
    char* ws = (char*)d_ws;
    const size_t OFF_PHI = 0;
    const size_t OFF_HS  = 33554432ull;
    const size_t OFF_WP  = 167772160ull;
    const size_t OFF_HX  = 170131456ull;
    const size_t OFF_CNT = 170655744ull;
    const size_t TOTAL   = 170663936ull;
    if (ws_size < TOTAL) return;
    unsigned short* phi   = (unsigned short*)(ws + OFF_PHI);
    float*          hsbuf = (float*)(ws + OFF_HS);
    unsigned short* wpack = (unsigned short*)(ws + OFF_WP);
    unsigned*       hx    = (unsigned*)(ws + OFF_HX);
    unsigned*       cnt   = (unsigned*)(ws + OFF_CNT);

    zero_init<<<dim3(256), 256, 0, stream>>>(hx, cnt, out);
    pack_w<<<dim3(512), 256, 0, stream>>>(W_ih, W_hh, wpack);
    embed_phi<<<dim3(1024), 256, 0, stream>>>(x, W_embed, b_embed, phi);

    void* args[] = {(void*)&wpack, (void*)&phi, (void*)&hx, (void*)&hsbuf,
                    (void*)&b_ih, (void*)&b_hh, (void*)&cnt,
                    (void*)&W_he, (void*)&b_he, (void*)&W_mu, (void*)&b_mu,
                    (void*)&W_lv, (void*)&b_lv, (void*)&h_inf, (void*)&tinf,
                    (void*)&bint, (void*)&x, (void*)&t_in, (void*)&mask, (void*)&out};
    hipLaunchCooperativeKernel((void*)fused_persist, dim3(256), dim3(384), args, 0, stream);
}